// Round 5
// baseline (385.419 us; speedup 1.0000x reference)
//
#include <hip/hip_runtime.h>
#include <cstdint>

// Problem constants (from reference): B=8192, DIN=DOUT=4096, NC=64
#define BB   8192
#define DIN  4096
#define DOUT 4096
#define NCL  64

typedef __bf16 bf16;
typedef __attribute__((ext_vector_type(8))) __bf16 bf16x8;
typedef __attribute__((ext_vector_type(4))) float   f32x4;

#define GAS(p) (reinterpret_cast<uint32_t __attribute__((address_space(1)))*>(reinterpret_cast<uintptr_t>(p)))
#define LAS(p) (reinterpret_cast<uint32_t __attribute__((address_space(3)))*>(reinterpret_cast<uintptr_t>(p)))

#define WAITV(n)  asm volatile("s_waitcnt vmcnt(" #n ")" ::: "memory")
#define WAITLN(n) asm volatile("s_waitcnt lgkmcnt(" #n ")" ::: "memory")
#define BARR()    __builtin_amdgcn_s_barrier()
#define SCHED0()  __builtin_amdgcn_sched_barrier(0)
#define MFMA(a, b, c) __builtin_amdgcn_mfma_f32_16x16x32_bf16((a), (b), (c), 0, 0, 0)

// ---------------------------------------------------------------------------
// Kernel 1 (fused prep): block-range dispatch.
//   blocks [0,2048):   prologue — tmpL = cluster@style_L (K=64 MFMA),
//                      A' = bf16(x*tmpL); bid<64 also dumps cluster as bf16.
//   blocks [2048,4096): W (DIN x DOUT f32) -> Wt (DOUT x DIN bf16)
//   blocks [4096,4112): style_R (64 x DOUT f32) -> sRt (DOUT x 64 bf16)
// ---------------------------------------------------------------------------
__global__ __launch_bounds__(256) void prep_kernel(
    const float* __restrict__ x, const float* __restrict__ cl,
    const float* __restrict__ sL, const float* __restrict__ sR,
    const float* __restrict__ W,
    bf16* __restrict__ Ap, bf16* __restrict__ clb,
    bf16* __restrict__ Wt, bf16* __restrict__ srt)
{
    __shared__ uint4 lds_u4[2048]; // 32 KiB (used by prologue branch only)
    const int bid = blockIdx.x;
    const int t   = threadIdx.x;

    if (bid < 2048) {
        // ---------------- prologue ----------------
        char* lds = (char*)lds_u4;
        const int lane = t & 63;
        const int w    = t >> 6;
        const int wm   = w >> 1, wn = w & 1;
        const int r0   = (bid & 63) * 128;
        const int c0   = (bid >> 6) * 128;

        #pragma unroll
        for (int i = 0; i < 4; i++) {
            int tk  = t + i * 256;
            int row = tk >> 3, ch = tk & 7;
            const float* src = cl + (size_t)(r0 + row) * NCL + ch * 8;
            float4 v0 = *(const float4*)src;
            float4 v1 = *(const float4*)(src + 4);
            bf16x8 pk;
            pk[0]=(bf16)v0.x; pk[1]=(bf16)v0.y; pk[2]=(bf16)v0.z; pk[3]=(bf16)v0.w;
            pk[4]=(bf16)v1.x; pk[5]=(bf16)v1.y; pk[6]=(bf16)v1.z; pk[7]=(bf16)v1.w;
            *(bf16x8*)(lds + row * 128 + ((ch ^ (row & 7)) << 4)) = pk;
            if (bid < 64)
                *(bf16x8*)(clb + (size_t)(r0 + row) * NCL + ch * 8) = pk;
        }
        #pragma unroll
        for (int i = 0; i < 4; i++) {
            int tk = t + i * 256;
            int n  = tk & 127, c = tk >> 7;
            bf16x8 pl;
            #pragma unroll
            for (int j = 0; j < 8; j++)
                pl[j] = (bf16)sL[(size_t)(c * 8 + j) * DIN + c0 + n];
            *(bf16x8*)(lds + 16384 + n * 128 + ((c ^ (n & 7)) << 4)) = pl;
        }
        __syncthreads();

        f32x4 accL[4][4] = {};
        #pragma unroll
        for (int s = 0; s < 2; s++) {
            bf16x8 a[4], bl[4];
            #pragma unroll
            for (int m = 0; m < 4; m++) {
                int row = wm * 64 + m * 16 + (lane & 15);
                int ch  = s * 4 + (lane >> 4);
                a[m] = *(bf16x8*)(lds + row * 128 + ((ch ^ (row & 7)) << 4));
            }
            #pragma unroll
            for (int n = 0; n < 4; n++) {
                int row = wn * 64 + n * 16 + (lane & 15);
                int ch  = s * 4 + (lane >> 4);
                bl[n] = *(bf16x8*)(lds + 16384 + row * 128 + ((ch ^ (row & 7)) << 4));
            }
            #pragma unroll
            for (int m = 0; m < 4; m++)
                #pragma unroll
                for (int n = 0; n < 4; n++)
                    accL[m][n] = MFMA(a[m], bl[n], accL[m][n]);
        }

        #pragma unroll
        for (int m = 0; m < 4; m++) {
            int rbase = r0 + wm * 64 + m * 16 + ((lane >> 4) << 2);
            #pragma unroll
            for (int n = 0; n < 4; n++) {
                int col = c0 + wn * 64 + n * 16 + (lane & 15);
                #pragma unroll
                for (int j = 0; j < 4; j++) {
                    size_t idx = (size_t)(rbase + j) * DIN + col;
                    Ap[idx] = (bf16)(x[idx] * accL[m][n][j]);
                }
            }
        }
    } else if (bid < 4096) {
        // ---------------- W transpose ----------------
        const int tb = bid - 2048;
        const int n  = (tb & 15) * 256 + t;
        const int k0 = (tb >> 4) * 32;
        bf16x8 v[4];
        #pragma unroll
        for (int q = 0; q < 4; q++)
            #pragma unroll
            for (int j = 0; j < 8; j++)
                v[q][j] = (bf16)W[(size_t)(k0 + q * 8 + j) * DOUT + n];
        bf16* dst = Wt + (size_t)n * DIN + k0;
        #pragma unroll
        for (int q = 0; q < 4; q++)
            *(bf16x8*)(dst + q * 8) = v[q];
    } else {
        // ---------------- style_R transpose ----------------
        const int o = (bid - 4096) * 256 + t;
        bf16x8 v[8];
        #pragma unroll
        for (int q = 0; q < 8; q++)
            #pragma unroll
            for (int j = 0; j < 8; j++)
                v[q][j] = (bf16)sR[(size_t)(q * 8 + j) * DOUT + o];
        bf16* dst = srt + (size_t)o * 64;
        #pragma unroll
        for (int q = 0; q < 8; q++)
            *(bf16x8*)(dst + q * 8) = v[q];
    }
}

// ---------------------------------------------------------------------------
// Kernel 2: 256x256-tile 8-phase GEMM with split-drain counted lgkmcnt.
// Staging/vmcnt schedule identical to R4 (proven). Per tile t:
//   P1: reads [a0k0+b01k0(6) | a0k1+b01k1(6) | b23(4)] (sched_barrier-pinned);
//       stage (t+1).Ah1->OB; BAR; lgkm(10); MFMA k0(8); lgkm(4); MFMA k1(8); BAR
//   P2: stage (t+2).Bh0->CB; BAR; lgkm(0); MFMA a0xb23 (16); BAR
//   P3: reads [a1k0(4) | a1k1(4)]; stage (t+2).Bh1->CB; BAR;
//       lgkm(4); MFMA a1xb23 k0(8); lgkm(0); MFMA k1(8); BAR
//   P4: stage (t+2).Ah0->CB; BAR; MFMA a1xb01 (16); vmcnt(6); BAR
// Then fused tmpR tile: acc *= (cluster @ style_R) over K=64.
// ---------------------------------------------------------------------------
template<int CUR>
__device__ __forceinline__ void tile_step(char* lds, int tid,
    const bf16* pA1, const bf16* pA2, const bf16* pA3, const bf16* pA4,
    const bf16* pB1, const bf16* pB2, const bf16* pB3, const bf16* pB4,
    int kA1, int kA2, int aoff0, int aoff1, int boff0, int boff1,
    bf16x8 a[4][2], bf16x8 b[4][2], f32x4 acc[8][4])
{
    constexpr int CB = CUR * 65536;
    constexpr int OB = (CUR ^ 1) * 65536;

    // ---------- P1 ----------
    // group1: a0 k0 (4) + b01 k0 (2)
    #pragma unroll
    for (int mq = 0; mq < 4; ++mq)
        a[mq][0] = *(const bf16x8*)(lds + CB + mq * 2048 + aoff0);
    b[0][0] = *(const bf16x8*)(lds + CB + 0 * 2048 + boff0);
    b[1][0] = *(const bf16x8*)(lds + CB + 1 * 2048 + boff0);
    SCHED0();
    // group2: a0 k1 (4) + b01 k1 (2)
    #pragma unroll
    for (int mq = 0; mq < 4; ++mq)
        a[mq][1] = *(const bf16x8*)(lds + CB + mq * 2048 + aoff1);
    b[0][1] = *(const bf16x8*)(lds + CB + 0 * 2048 + boff1);
    b[1][1] = *(const bf16x8*)(lds + CB + 1 * 2048 + boff1);
    SCHED0();
    // group3: b23 (4)
    b[2][0] = *(const bf16x8*)(lds + CB + 2 * 2048 + boff0);
    b[3][0] = *(const bf16x8*)(lds + CB + 3 * 2048 + boff0);
    b[2][1] = *(const bf16x8*)(lds + CB + 2 * 2048 + boff1);
    b[3][1] = *(const bf16x8*)(lds + CB + 3 * 2048 + boff1);
    __builtin_amdgcn_global_load_lds(GAS(pA3 + kA1), LAS(lds + OB + 16384 + tid * 16), 16, 0, 0);
    __builtin_amdgcn_global_load_lds(GAS(pA4 + kA1), LAS(lds + OB + 24576 + tid * 16), 16, 0, 0);
    BARR();
    WAITLN(10); SCHED0();
    __builtin_amdgcn_s_setprio(1);
    #pragma unroll
    for (int mq = 0; mq < 4; ++mq)
        #pragma unroll
        for (int nq = 0; nq < 2; ++nq)
            acc[mq][nq] = MFMA(a[mq][0], b[nq][0], acc[mq][nq]);
    WAITLN(4); SCHED0();
    #pragma unroll
    for (int mq = 0; mq < 4; ++mq)
        #pragma unroll
        for (int nq = 0; nq < 2; ++nq)
            acc[mq][nq] = MFMA(a[mq][1], b[nq][1], acc[mq][nq]);
    __builtin_amdgcn_s_setprio(0);
    BARR();

    // ---------- P2 ----------
    __builtin_amdgcn_global_load_lds(GAS(pB1 + kA2), LAS(lds + CB + 32768 + tid * 16), 16, 0, 0);
    __builtin_amdgcn_global_load_lds(GAS(pB2 + kA2), LAS(lds + CB + 40960 + tid * 16), 16, 0, 0);
    BARR();
    WAITLN(0); SCHED0();   // drain group3 (b23) — long completed under P1's MFMA
    __builtin_amdgcn_s_setprio(1);
    #pragma unroll
    for (int k = 0; k < 2; ++k)
        #pragma unroll
        for (int mq = 0; mq < 4; ++mq)
            #pragma unroll
            for (int nq = 0; nq < 2; ++nq)
                acc[mq][2 + nq] = MFMA(a[mq][k], b[2 + nq][k], acc[mq][2 + nq]);
    __builtin_amdgcn_s_setprio(0);
    BARR();

    // ---------- P3 ----------
    // group1: a1 k0 (4)
    #pragma unroll
    for (int mq = 0; mq < 4; ++mq)
        a[mq][0] = *(const bf16x8*)(lds + CB + 8192 + mq * 2048 + aoff0);
    SCHED0();
    // group2: a1 k1 (4)
    #pragma unroll
    for (int mq = 0; mq < 4; ++mq)
        a[mq][1] = *(const bf16x8*)(lds + CB + 8192 + mq * 2048 + aoff1);
    __builtin_amdgcn_global_load_lds(GAS(pB3 + kA2), LAS(lds + CB + 49152 + tid * 16), 16, 0, 0);
    __builtin_amdgcn_global_load_lds(GAS(pB4 + kA2), LAS(lds + CB + 57344 + tid * 16), 16, 0, 0);
    BARR();
    WAITLN(4); SCHED0();
    __builtin_amdgcn_s_setprio(1);
    #pragma unroll
    for (int mq = 0; mq < 4; ++mq)
        #pragma unroll
        for (int nq = 0; nq < 2; ++nq)
            acc[4 + mq][2 + nq] = MFMA(a[mq][0], b[2 + nq][0], acc[4 + mq][2 + nq]);
    WAITLN(0); SCHED0();
    #pragma unroll
    for (int mq = 0; mq < 4; ++mq)
        #pragma unroll
        for (int nq = 0; nq < 2; ++nq)
            acc[4 + mq][2 + nq] = MFMA(a[mq][1], b[2 + nq][1], acc[4 + mq][2 + nq]);
    __builtin_amdgcn_s_setprio(0);
    BARR();

    // ---------- P4 ----------
    __builtin_amdgcn_global_load_lds(GAS(pA1 + kA2), LAS(lds + CB + tid * 16), 16, 0, 0);
    __builtin_amdgcn_global_load_lds(GAS(pA2 + kA2), LAS(lds + CB + 8192 + tid * 16), 16, 0, 0);
    BARR();
    __builtin_amdgcn_s_setprio(1);
    #pragma unroll
    for (int k = 0; k < 2; ++k)
        #pragma unroll
        for (int mq = 0; mq < 4; ++mq)
            #pragma unroll
            for (int nq = 0; nq < 2; ++nq)
                acc[4 + mq][nq] = MFMA(a[mq][k], b[nq][k], acc[4 + mq][nq]);
    __builtin_amdgcn_s_setprio(0);
    WAITV(6);
    BARR();
}

__global__ __launch_bounds__(512, 2) void gemm_kernel(
    const bf16* __restrict__ Ap, const bf16* __restrict__ Wt,
    const bf16* __restrict__ clb, const bf16* __restrict__ srt,
    float* __restrict__ out)
{
    __shared__ uint4 smem[8192]; // 128 KiB
    char* lds = (char*)smem;
    const int tid  = threadIdx.x;
    const int lane = tid & 63;
    const int w    = tid >> 6;
    const int wm   = w >> 2;   // 0..1
    const int wn   = w & 3;    // 0..3
    const int L = lane & 15, H = lane >> 4;

    // XCD-bijective swizzle: 512 blocks, 8 XCDs, 64 tiles each (4 mt x 16 nt)
    const int bid = blockIdx.x;
    const int xc  = bid & 7, ii = bid >> 3;
    const int mt  = xc * 4 + (ii >> 4);
    const int nt  = ii & 15;
    const size_t brow = (size_t)mt * 256;
    const size_t bcol = (size_t)nt * 256;

    // staging: dest linear (tid*16), source chunk inverse-swizzled
    const int r1  = tid >> 3;
    const int gch = (tid & 7) ^ (r1 & 7);
    const bf16* pA1 = Ap + (brow + r1) * (size_t)DIN + gch * 8;
    const bf16* pA2 = pA1 + (size_t)64  * DIN;
    const bf16* pA3 = pA1 + (size_t)128 * DIN;
    const bf16* pA4 = pA1 + (size_t)192 * DIN;
    const bf16* pB1 = Wt + (bcol + r1) * (size_t)DIN + gch * 8;
    const bf16* pB2 = pB1 + (size_t)64  * DIN;
    const bf16* pB3 = pB1 + (size_t)128 * DIN;
    const bf16* pB4 = pB1 + (size_t)192 * DIN;

    // fragment ds_read offsets: chunk = kk*4+H, slot = chunk^(L&7)
    const int swz0 = (H ^ (L & 7)) << 4;
    const int swz1 = ((4 + H) ^ (L & 7)) << 4;
    const int aoff0 = wm * 16384 + L * 128 + swz0;
    const int aoff1 = wm * 16384 + L * 128 + swz1;
    const int boff0 = 32768 + (wn >> 1) * 16384 + (wn & 1) * 8192 + L * 128 + swz0;
    const int boff1 = 32768 + (wn >> 1) * 16384 + (wn & 1) * 8192 + L * 128 + swz1;

    bf16x8 a[4][2], b[4][2];
    f32x4 acc[8][4] = {};

    // prologue: tile0 all 4 pieces -> buf0; tile1 {Bh0,Bh1,Ah0} -> buf1
    __builtin_amdgcn_global_load_lds(GAS(pA1), LAS(lds + tid * 16), 16, 0, 0);
    __builtin_amdgcn_global_load_lds(GAS(pA2), LAS(lds + 8192 + tid * 16), 16, 0, 0);
    __builtin_amdgcn_global_load_lds(GAS(pA3), LAS(lds + 16384 + tid * 16), 16, 0, 0);
    __builtin_amdgcn_global_load_lds(GAS(pA4), LAS(lds + 24576 + tid * 16), 16, 0, 0);
    __builtin_amdgcn_global_load_lds(GAS(pB1), LAS(lds + 32768 + tid * 16), 16, 0, 0);
    __builtin_amdgcn_global_load_lds(GAS(pB2), LAS(lds + 40960 + tid * 16), 16, 0, 0);
    __builtin_amdgcn_global_load_lds(GAS(pB3), LAS(lds + 49152 + tid * 16), 16, 0, 0);
    __builtin_amdgcn_global_load_lds(GAS(pB4), LAS(lds + 57344 + tid * 16), 16, 0, 0);
    __builtin_amdgcn_global_load_lds(GAS(pB1 + 64), LAS(lds + 65536 + 32768 + tid * 16), 16, 0, 0);
    __builtin_amdgcn_global_load_lds(GAS(pB2 + 64), LAS(lds + 65536 + 40960 + tid * 16), 16, 0, 0);
    __builtin_amdgcn_global_load_lds(GAS(pB3 + 64), LAS(lds + 65536 + 49152 + tid * 16), 16, 0, 0);
    __builtin_amdgcn_global_load_lds(GAS(pB4 + 64), LAS(lds + 65536 + 57344 + tid * 16), 16, 0, 0);
    __builtin_amdgcn_global_load_lds(GAS(pA1 + 64), LAS(lds + 65536 + tid * 16), 16, 0, 0);
    __builtin_amdgcn_global_load_lds(GAS(pA2 + 64), LAS(lds + 65536 + 8192 + tid * 16), 16, 0, 0);
    WAITV(6);
    BARR();

    #pragma unroll 1
    for (int t = 0; t < 64; t += 2) {
        tile_step<0>(lds, tid, pA1, pA2, pA3, pA4, pB1, pB2, pB3, pB4,
                     ((t + 1) & 63) * 64, ((t + 2) & 63) * 64,
                     aoff0, aoff1, boff0, boff1, a, b, acc);
        tile_step<1>(lds, tid, pA1, pA2, pA3, pA4, pB1, pB2, pB3, pB4,
                     ((t + 2) & 63) * 64, ((t + 3) & 63) * 64,
                     aoff0, aoff1, boff0, boff1, a, b, acc);
    }

    // ---- fused tmpR tile: acc *= (cluster @ style_R) over K=64 ----
    WAITV(0);                    // drain wrap-around junk prefetches
    const bf16* pC = clb + (brow + r1) * 64 + gch * 8;
    const bf16* pR = srt + (bcol + r1) * 64 + gch * 8;
    __builtin_amdgcn_global_load_lds(GAS(pC),         LAS(lds + tid * 16), 16, 0, 0);
    __builtin_amdgcn_global_load_lds(GAS(pC + 4096),  LAS(lds + 8192 + tid * 16), 16, 0, 0);
    __builtin_amdgcn_global_load_lds(GAS(pC + 8192),  LAS(lds + 16384 + tid * 16), 16, 0, 0);
    __builtin_amdgcn_global_load_lds(GAS(pC + 12288), LAS(lds + 24576 + tid * 16), 16, 0, 0);
    __builtin_amdgcn_global_load_lds(GAS(pR),         LAS(lds + 32768 + tid * 16), 16, 0, 0);
    __builtin_amdgcn_global_load_lds(GAS(pR + 4096),  LAS(lds + 40960 + tid * 16), 16, 0, 0);
    __builtin_amdgcn_global_load_lds(GAS(pR + 8192),  LAS(lds + 49152 + tid * 16), 16, 0, 0);
    __builtin_amdgcn_global_load_lds(GAS(pR + 12288), LAS(lds + 57344 + tid * 16), 16, 0, 0);
    WAITV(0);
    BARR();

    #pragma unroll
    for (int nb = 0; nb < 4; ++nb) {
        b[nb][0] = *(const bf16x8*)(lds + nb * 2048 + boff0);
        b[nb][1] = *(const bf16x8*)(lds + nb * 2048 + boff1);
    }
    #pragma unroll
    for (int half = 0; half < 2; ++half) {
        #pragma unroll
        for (int mq = 0; mq < 4; ++mq) {
            a[mq][0] = *(const bf16x8*)(lds + half * 8192 + mq * 2048 + aoff0);
            a[mq][1] = *(const bf16x8*)(lds + half * 8192 + mq * 2048 + aoff1);
        }
        WAITLN(0); SCHED0();
        f32x4 r4[4][4] = {};
        #pragma unroll
        for (int k = 0; k < 2; ++k)
            #pragma unroll
            for (int mq = 0; mq < 4; ++mq)
                #pragma unroll
                for (int nb = 0; nb < 4; ++nb)
                    r4[mq][nb] = MFMA(a[mq][k], b[nb][k], r4[mq][nb]);
        #pragma unroll
        for (int mq = 0; mq < 4; ++mq)
            #pragma unroll
            for (int nb = 0; nb < 4; ++nb)
                acc[half * 4 + mq][nb] *= r4[mq][nb];
    }

    // epilogue: out = acc (already modulated), f32 stores
    #pragma unroll
    for (int m = 0; m < 8; m++) {
        size_t rbase = brow + (size_t)(wm * 128 + m * 16 + (H << 2));
        #pragma unroll
        for (int n = 0; n < 4; n++) {
            size_t col = bcol + (size_t)(wn * 64 + n * 16 + L);
            #pragma unroll
            for (int j = 0; j < 4; j++) {
                size_t idx = (rbase + j) * DOUT + col;
                out[idx] = acc[m][n][j];
            }
        }
    }
}

// ---------------------------------------------------------------------------
extern "C" void kernel_launch(void* const* d_in, const int* in_sizes, int n_in,
                              void* d_out, int out_size, void* d_ws, size_t ws_size,
                              hipStream_t stream)
{
    (void)in_sizes; (void)n_in; (void)out_size;
    const float* x  = (const float*)d_in[0];
    const float* cl = (const float*)d_in[1];
    const float* W  = (const float*)d_in[2];
    const float* sL = (const float*)d_in[3];
    const float* sR = (const float*)d_in[4];
    float* out = (float*)d_out;

    // ws: A' (64MiB) | Wt (32MiB) | clb (1MiB) | srt (0.5MiB)
    const size_t AP_BYTES = (size_t)BB * DIN * sizeof(bf16);
    const size_t WT_BYTES = (size_t)DIN * DOUT * sizeof(bf16);
    const size_t CL_BYTES = (size_t)BB * NCL * sizeof(bf16);
    const size_t SR_BYTES = (size_t)DOUT * NCL * sizeof(bf16);
    if (ws_size < AP_BYTES + WT_BYTES + CL_BYTES + SR_BYTES) return;

    char* ws = (char*)d_ws;
    bf16* Ap  = (bf16*)ws;
    bf16* Wt  = (bf16*)(ws + AP_BYTES);
    bf16* clb = (bf16*)(ws + AP_BYTES + WT_BYTES);
    bf16* srt = (bf16*)(ws + AP_BYTES + WT_BYTES + CL_BYTES);

    prep_kernel<<<dim3(4112), 256, 0, stream>>>(x, cl, sL, sR, W, Ap, clb, Wt, srt);
    gemm_kernel<<<dim3((BB / 256) * (DOUT / 256)), 512, 0, stream>>>(Ap, Wt, clb, srt, out);
}

// Round 6
// 365.414 us; speedup vs baseline: 1.0547x; 1.0547x over previous
//
#include <hip/hip_runtime.h>
#include <cstdint>

// Problem constants (from reference): B=8192, DIN=DOUT=4096, NC=64
#define BB   8192
#define DIN  4096
#define DOUT 4096
#define NCL  64

typedef __bf16 bf16;
typedef __attribute__((ext_vector_type(8)))  __bf16 bf16x8;
typedef __attribute__((ext_vector_type(4)))  float  f32x4;
typedef __attribute__((ext_vector_type(16))) float  f32x16;

#define GAS(p) (reinterpret_cast<uint32_t __attribute__((address_space(1)))*>(reinterpret_cast<uintptr_t>(p)))
#define LAS(p) (reinterpret_cast<uint32_t __attribute__((address_space(3)))*>(reinterpret_cast<uintptr_t>(p)))

#define WAITV(n)  asm volatile("s_waitcnt vmcnt(" #n ")" ::: "memory")
#define WAITLN(n) asm volatile("s_waitcnt lgkmcnt(" #n ")" ::: "memory")
#define WAITL()   asm volatile("s_waitcnt lgkmcnt(0)" ::: "memory")
#define BARR()    __builtin_amdgcn_s_barrier()
#define SCHED0()  __builtin_amdgcn_sched_barrier(0)
#define MFMA16(a, b, c) __builtin_amdgcn_mfma_f32_16x16x32_bf16((a), (b), (c), 0, 0, 0)
#define MFMA32(a, b, c) __builtin_amdgcn_mfma_f32_32x32x16_bf16((a), (b), (c), 0, 0, 0)

// ---------------------------------------------------------------------------
// Kernel 1: prologue (R4-proven, separate kernel). tmpL = cluster @ style_L
// (K=64 MFMA); writes A' = bf16(x*tmpL). blockIdx.y==0 blocks also dump the
// cluster tile as bf16 (B x 64) for the GEMM's fused-tmpR tile.
// ---------------------------------------------------------------------------
__global__ __launch_bounds__(256) void prologue_kernel(
    const float* __restrict__ x, const float* __restrict__ cl,
    const float* __restrict__ sL, bf16* __restrict__ Ap,
    bf16* __restrict__ clb)
{
    __shared__ uint4 lds_u4[2048]; // 32 KiB
    char* lds = (char*)lds_u4;
    const int t    = threadIdx.x;
    const int lane = t & 63;
    const int w    = t >> 6;
    const int wm   = w >> 1, wn = w & 1;
    const int r0   = blockIdx.x * 128;
    const int c0   = blockIdx.y * 128;

    #pragma unroll
    for (int i = 0; i < 4; i++) {
        int tk  = t + i * 256;
        int row = tk >> 3, ch = tk & 7;
        const float* src = cl + (size_t)(r0 + row) * NCL + ch * 8;
        float4 v0 = *(const float4*)src;
        float4 v1 = *(const float4*)(src + 4);
        bf16x8 pk;
        pk[0]=(bf16)v0.x; pk[1]=(bf16)v0.y; pk[2]=(bf16)v0.z; pk[3]=(bf16)v0.w;
        pk[4]=(bf16)v1.x; pk[5]=(bf16)v1.y; pk[6]=(bf16)v1.z; pk[7]=(bf16)v1.w;
        *(bf16x8*)(lds + row * 128 + ((ch ^ (row & 7)) << 4)) = pk;
        if (blockIdx.y == 0)
            *(bf16x8*)(clb + (size_t)(r0 + row) * NCL + ch * 8) = pk;
    }
    #pragma unroll
    for (int i = 0; i < 4; i++) {
        int tk = t + i * 256;
        int n  = tk & 127, c = tk >> 7;
        bf16x8 pl;
        #pragma unroll
        for (int j = 0; j < 8; j++)
            pl[j] = (bf16)sL[(size_t)(c * 8 + j) * DIN + c0 + n];
        *(bf16x8*)(lds + 16384 + n * 128 + ((c ^ (n & 7)) << 4)) = pl;
    }
    __syncthreads();

    f32x4 accL[4][4] = {};
    #pragma unroll
    for (int s = 0; s < 2; s++) {
        bf16x8 a[4], bl[4];
        #pragma unroll
        for (int m = 0; m < 4; m++) {
            int row = wm * 64 + m * 16 + (lane & 15);
            int ch  = s * 4 + (lane >> 4);
            a[m] = *(bf16x8*)(lds + row * 128 + ((ch ^ (row & 7)) << 4));
        }
        #pragma unroll
        for (int n = 0; n < 4; n++) {
            int row = wn * 64 + n * 16 + (lane & 15);
            int ch  = s * 4 + (lane >> 4);
            bl[n] = *(bf16x8*)(lds + 16384 + row * 128 + ((ch ^ (row & 7)) << 4));
        }
        #pragma unroll
        for (int m = 0; m < 4; m++)
            #pragma unroll
            for (int n = 0; n < 4; n++)
                accL[m][n] = MFMA16(a[m], bl[n], accL[m][n]);
    }

    #pragma unroll
    for (int m = 0; m < 4; m++) {
        int rbase = r0 + wm * 64 + m * 16 + ((lane >> 4) << 2);
        #pragma unroll
        for (int n = 0; n < 4; n++) {
            int col = c0 + wn * 64 + n * 16 + (lane & 15);
            #pragma unroll
            for (int j = 0; j < 4; j++) {
                size_t idx = (size_t)(rbase + j) * DIN + col;
                Ap[idx] = (bf16)(x[idx] * accL[m][n][j]);
            }
        }
    }
}

// ---------------------------------------------------------------------------
// Kernel 2: W (DIN x DOUT f32) -> Wt (DOUT x DIN bf16)
// ---------------------------------------------------------------------------
__global__ __launch_bounds__(256) void transpose_kernel(
    const float* __restrict__ W, bf16* __restrict__ Wt)
{
    const int t  = threadIdx.x;
    const int n  = blockIdx.x * 256 + t;
    const int k0 = blockIdx.y * 32;
    bf16x8 v[4];
    #pragma unroll
    for (int q = 0; q < 4; q++)
        #pragma unroll
        for (int j = 0; j < 8; j++)
            v[q][j] = (bf16)W[(size_t)(k0 + q * 8 + j) * DOUT + n];
    bf16* dst = Wt + (size_t)n * DIN + k0;
    #pragma unroll
    for (int q = 0; q < 4; q++)
        *(bf16x8*)(dst + q * 8) = v[q];
}

// ---------------------------------------------------------------------------
// Kernel 2b: style_R (64 x DOUT f32) -> sRt (DOUT x 64 bf16)
// ---------------------------------------------------------------------------
__global__ __launch_bounds__(256) void srt_kernel(
    const float* __restrict__ sR, bf16* __restrict__ srt)
{
    const int o = blockIdx.x * 256 + threadIdx.x;
    bf16x8 v[8];
    #pragma unroll
    for (int q = 0; q < 8; q++)
        #pragma unroll
        for (int j = 0; j < 8; j++)
            v[q][j] = (bf16)sR[(size_t)(q * 8 + j) * DOUT + o];
    bf16* dst = srt + (size_t)o * 64;
    #pragma unroll
    for (int q = 0; q < 8; q++)
        *(bf16x8*)(dst + q * 8) = v[q];
}

// ---------------------------------------------------------------------------
// Kernel 3: 256x256 8-phase GEMM on v_mfma_f32_32x32x16_bf16 (+fused tmpR).
// 512 thr = 8 waves (2M x 4N); per wave: 4 m-frags (32 rows) x 2 n-frags.
//   rows_base(mf) = (mf>>1)*128 + wm*64 + (mf&1)*32   (mf 0,1 in Ah0; 2,3 Ah1)
//   col_base(nf)  = nf*128 + wn*32                    (nf 0 in Bh0; 1 in Bh1)
// A/B frag (lane l): row/col = l&31, k = (l>>5)*8 + j  [family pattern]
// C/D (m74/m101): col = l&31, row = (reg&3) + 8*(reg>>2) + 4*(l>>5)
// Phases/tile (CB = buf[t&1]):  (piece dies exactly one phase before re-stage)
//   P1: ds aL(8)+b0(4); stage (t+1).Ah1->OB; lgkm(8); BAR; lgkm0; 8 MFMA aL*b0; BAR
//   P2: ds b1(4);       stage (t+2).Ah0->CB; BAR; lgkm0; 8 MFMA aL*b1; BAR
//   P3: ds aH(8);       stage (t+2).Bh0->CB; BAR; lgkm0; 8 MFMA aH*b1; BAR
//   P4: (no reads)      stage (t+2).Bh1->CB; BAR; 8 MFMA aH*b0; vmcnt(6); BAR
// vmcnt(6) once/tile: leaves exactly P2..P4's 6 loads (t+2 pieces) in flight,
// guaranteeing all of tile t+1 is resident. b0 regs live P1->P4 (LDS dies P1).
// ---------------------------------------------------------------------------
template<int CUR>
__device__ __forceinline__ void tile_step(char* lds, int tid,
    const bf16* pA1, const bf16* pA2, const bf16* pA3, const bf16* pA4,
    const bf16* pB1, const bf16* pB2, const bf16* pB3, const bf16* pB4,
    int kA1, int kA2, int arow, int brow,
    int ks0, int ks1, int ks2, int ks3,
    bf16x8 (&a)[2][4], bf16x8 (&b0)[4], bf16x8 (&b1)[4], f32x16 (&acc)[4][2])
{
    constexpr int CB = CUR * 65536;
    constexpr int OB = (CUR ^ 1) * 65536;
    const int ks[4] = {ks0, ks1, ks2, ks3};

    // ---------- P1 ----------
    #pragma unroll
    for (int f = 0; f < 2; ++f)
        #pragma unroll
        for (int kk = 0; kk < 4; ++kk)
            a[f][kk] = *(const bf16x8*)(lds + CB + f * 4096 + arow + ks[kk]);
    #pragma unroll
    for (int kk = 0; kk < 4; ++kk)
        b0[kk] = *(const bf16x8*)(lds + CB + 32768 + brow + ks[kk]);
    __builtin_amdgcn_global_load_lds(GAS(pA3 + kA1), LAS(lds + OB + 16384 + tid * 16), 16, 0, 0);
    __builtin_amdgcn_global_load_lds(GAS(pA4 + kA1), LAS(lds + OB + 24576 + tid * 16), 16, 0, 0);
    WAITLN(8);
    BARR();
    WAITL(); SCHED0();
    __builtin_amdgcn_s_setprio(1);
    #pragma unroll
    for (int kk = 0; kk < 4; ++kk)
        #pragma unroll
        for (int f = 0; f < 2; ++f)
            acc[f][0] = MFMA32(a[f][kk], b0[kk], acc[f][0]);
    __builtin_amdgcn_s_setprio(0);
    BARR();

    // ---------- P2 ----------
    #pragma unroll
    for (int kk = 0; kk < 4; ++kk)
        b1[kk] = *(const bf16x8*)(lds + CB + 49152 + brow + ks[kk]);
    __builtin_amdgcn_global_load_lds(GAS(pA1 + kA2), LAS(lds + CB + tid * 16), 16, 0, 0);
    __builtin_amdgcn_global_load_lds(GAS(pA2 + kA2), LAS(lds + CB + 8192 + tid * 16), 16, 0, 0);
    BARR();
    WAITL(); SCHED0();
    __builtin_amdgcn_s_setprio(1);
    #pragma unroll
    for (int kk = 0; kk < 4; ++kk)
        #pragma unroll
        for (int f = 0; f < 2; ++f)
            acc[f][1] = MFMA32(a[f][kk], b1[kk], acc[f][1]);
    __builtin_amdgcn_s_setprio(0);
    BARR();

    // ---------- P3 ----------
    #pragma unroll
    for (int f = 0; f < 2; ++f)
        #pragma unroll
        for (int kk = 0; kk < 4; ++kk)
            a[f][kk] = *(const bf16x8*)(lds + CB + 16384 + f * 4096 + arow + ks[kk]);
    __builtin_amdgcn_global_load_lds(GAS(pB1 + kA2), LAS(lds + CB + 32768 + tid * 16), 16, 0, 0);
    __builtin_amdgcn_global_load_lds(GAS(pB2 + kA2), LAS(lds + CB + 40960 + tid * 16), 16, 0, 0);
    BARR();
    WAITL(); SCHED0();
    __builtin_amdgcn_s_setprio(1);
    #pragma unroll
    for (int kk = 0; kk < 4; ++kk)
        #pragma unroll
        for (int f = 0; f < 2; ++f)
            acc[2 + f][1] = MFMA32(a[f][kk], b1[kk], acc[2 + f][1]);
    __builtin_amdgcn_s_setprio(0);
    BARR();

    // ---------- P4 ----------
    __builtin_amdgcn_global_load_lds(GAS(pB3 + kA2), LAS(lds + CB + 49152 + tid * 16), 16, 0, 0);
    __builtin_amdgcn_global_load_lds(GAS(pB4 + kA2), LAS(lds + CB + 57344 + tid * 16), 16, 0, 0);
    BARR();
    __builtin_amdgcn_s_setprio(1);
    #pragma unroll
    for (int kk = 0; kk < 4; ++kk)
        #pragma unroll
        for (int f = 0; f < 2; ++f)
            acc[2 + f][0] = MFMA32(a[f][kk], b0[kk], acc[2 + f][0]);
    __builtin_amdgcn_s_setprio(0);
    WAITV(6);
    BARR();
}

__global__ __launch_bounds__(512, 2) void gemm_kernel(
    const bf16* __restrict__ Ap, const bf16* __restrict__ Wt,
    const bf16* __restrict__ clb, const bf16* __restrict__ srt,
    float* __restrict__ out)
{
    __shared__ uint4 smem[8192]; // 128 KiB
    char* lds = (char*)smem;
    const int tid  = threadIdx.x;
    const int lane = tid & 63;
    const int w    = tid >> 6;
    const int wm   = w >> 2;   // 0..1
    const int wn   = w & 3;    // 0..3
    const int L5 = lane & 31, H1 = lane >> 5;

    // XCD-bijective swizzle: 512 blocks, 8 XCDs, 64 tiles each (4 mt x 16 nt)
    const int bid = blockIdx.x;
    const int xc  = bid & 7, ii = bid >> 3;
    const int mt  = xc * 4 + (ii >> 4);
    const int nt  = ii & 15;
    const size_t brow_g = (size_t)mt * 256;
    const size_t bcol_g = (size_t)nt * 256;

    // staging: dest linear (tid*16), source chunk inverse-swizzled
    const int r1  = tid >> 3;
    const int gch = (tid & 7) ^ (r1 & 7);
    const bf16* pA1 = Ap + (brow_g + r1) * (size_t)DIN + gch * 8;
    const bf16* pA2 = pA1 + (size_t)64  * DIN;
    const bf16* pA3 = pA1 + (size_t)128 * DIN;
    const bf16* pA4 = pA1 + (size_t)192 * DIN;
    const bf16* pB1 = Wt + (bcol_g + r1) * (size_t)DIN + gch * 8;
    const bf16* pB2 = pB1 + (size_t)64  * DIN;
    const bf16* pB3 = pB1 + (size_t)128 * DIN;
    const bf16* pB4 = pB1 + (size_t)192 * DIN;

    // fragment ds_read offsets: chunk = kk*2 + H1, slot = chunk ^ (L5&7)
    const int ks0 = (((0 * 2 + H1) ^ (L5 & 7)) << 4);
    const int ks1 = (((1 * 2 + H1) ^ (L5 & 7)) << 4);
    const int ks2 = (((2 * 2 + H1) ^ (L5 & 7)) << 4);
    const int ks3 = (((3 * 2 + H1) ^ (L5 & 7)) << 4);
    const int arow = (wm * 64 + L5) * 128;  // in-piece; +4096 per m-subfrag
    const int brow = (wn * 32 + L5) * 128;  // in-piece

    bf16x8 a[2][4], b0[4], b1[4];
    f32x16 acc[4][2] = {};

    // prologue: tile0 all 4 pieces -> buf0; tile1 {Ah0,Bh0,Bh1} -> buf1
    __builtin_amdgcn_global_load_lds(GAS(pA1), LAS(lds + tid * 16), 16, 0, 0);
    __builtin_amdgcn_global_load_lds(GAS(pA2), LAS(lds + 8192 + tid * 16), 16, 0, 0);
    __builtin_amdgcn_global_load_lds(GAS(pA3), LAS(lds + 16384 + tid * 16), 16, 0, 0);
    __builtin_amdgcn_global_load_lds(GAS(pA4), LAS(lds + 24576 + tid * 16), 16, 0, 0);
    __builtin_amdgcn_global_load_lds(GAS(pB1), LAS(lds + 32768 + tid * 16), 16, 0, 0);
    __builtin_amdgcn_global_load_lds(GAS(pB2), LAS(lds + 40960 + tid * 16), 16, 0, 0);
    __builtin_amdgcn_global_load_lds(GAS(pB3), LAS(lds + 49152 + tid * 16), 16, 0, 0);
    __builtin_amdgcn_global_load_lds(GAS(pB4), LAS(lds + 57344 + tid * 16), 16, 0, 0);
    __builtin_amdgcn_global_load_lds(GAS(pA1 + 64), LAS(lds + 65536 + tid * 16), 16, 0, 0);
    __builtin_amdgcn_global_load_lds(GAS(pA2 + 64), LAS(lds + 65536 + 8192 + tid * 16), 16, 0, 0);
    __builtin_amdgcn_global_load_lds(GAS(pB1 + 64), LAS(lds + 65536 + 32768 + tid * 16), 16, 0, 0);
    __builtin_amdgcn_global_load_lds(GAS(pB2 + 64), LAS(lds + 65536 + 40960 + tid * 16), 16, 0, 0);
    __builtin_amdgcn_global_load_lds(GAS(pB3 + 64), LAS(lds + 65536 + 49152 + tid * 16), 16, 0, 0);
    __builtin_amdgcn_global_load_lds(GAS(pB4 + 64), LAS(lds + 65536 + 57344 + tid * 16), 16, 0, 0);
    WAITV(6);
    BARR();

    #pragma unroll 1
    for (int t = 0; t < 64; t += 2) {
        tile_step<0>(lds, tid, pA1, pA2, pA3, pA4, pB1, pB2, pB3, pB4,
                     ((t + 1) & 63) * 64, ((t + 2) & 63) * 64,
                     arow, brow, ks0, ks1, ks2, ks3, a, b0, b1, acc);
        tile_step<1>(lds, tid, pA1, pA2, pA3, pA4, pB1, pB2, pB3, pB4,
                     ((t + 2) & 63) * 64, ((t + 3) & 63) * 64,
                     arow, brow, ks0, ks1, ks2, ks3, a, b0, b1, acc);
    }

    // ---- fused tmpR tile: acc *= (cluster @ style_R) over K=64 ----
    WAITV(0);                    // drain wrap-around junk prefetches
    const bf16* pC = clb + (brow_g + r1) * 64 + gch * 8;
    const bf16* pR = srt + (bcol_g + r1) * 64 + gch * 8;
    __builtin_amdgcn_global_load_lds(GAS(pC),         LAS(lds + tid * 16), 16, 0, 0);
    __builtin_amdgcn_global_load_lds(GAS(pC + 4096),  LAS(lds + 8192 + tid * 16), 16, 0, 0);
    __builtin_amdgcn_global_load_lds(GAS(pC + 8192),  LAS(lds + 16384 + tid * 16), 16, 0, 0);
    __builtin_amdgcn_global_load_lds(GAS(pC + 12288), LAS(lds + 24576 + tid * 16), 16, 0, 0);
    __builtin_amdgcn_global_load_lds(GAS(pR),         LAS(lds + 32768 + tid * 16), 16, 0, 0);
    __builtin_amdgcn_global_load_lds(GAS(pR + 4096),  LAS(lds + 40960 + tid * 16), 16, 0, 0);
    __builtin_amdgcn_global_load_lds(GAS(pR + 8192),  LAS(lds + 49152 + tid * 16), 16, 0, 0);
    __builtin_amdgcn_global_load_lds(GAS(pR + 12288), LAS(lds + 57344 + tid * 16), 16, 0, 0);
    WAITV(0);
    BARR();

    const int ks[4] = {ks0, ks1, ks2, ks3};
    bf16x8 cb[2][4];
    #pragma unroll
    for (int nf = 0; nf < 2; ++nf)
        #pragma unroll
        for (int kk = 0; kk < 4; ++kk)
            cb[nf][kk] = *(const bf16x8*)(lds + 32768 + (nf * 2 + (wn >> 1)) * 8192
                                          + ((wn & 1) * 32 + L5) * 128 + ks[kk]);
    #pragma unroll
    for (int mf = 0; mf < 4; ++mf) {
        bf16x8 ca[4];
        #pragma unroll
        for (int kk = 0; kk < 4; ++kk)
            ca[kk] = *(const bf16x8*)(lds + ((mf >> 1) * 2 + wm) * 8192
                                      + ((mf & 1) * 32 + L5) * 128 + ks[kk]);
        WAITL(); SCHED0();
        #pragma unroll
        for (int nf = 0; nf < 2; ++nf) {
            f32x16 r = {};
            #pragma unroll
            for (int kk = 0; kk < 4; ++kk)
                r = MFMA32(ca[kk], cb[nf][kk], r);
            acc[mf][nf] *= r;
        }
    }

    // epilogue: out = acc (already modulated); C/D: col=L5, row=(reg&3)+8*(reg>>2)+4*H1
    #pragma unroll
    for (int mf = 0; mf < 4; ++mf) {
        size_t rbase = brow_g + (size_t)((mf >> 1) * 128 + wm * 64 + (mf & 1) * 32 + 4 * H1);
        #pragma unroll
        for (int nf = 0; nf < 2; ++nf) {
            size_t col = bcol_g + (size_t)(nf * 128 + wn * 32 + L5);
            #pragma unroll
            for (int reg = 0; reg < 16; ++reg) {
                size_t row = rbase + (reg & 3) + 8 * (reg >> 2);
                out[row * DOUT + col] = acc[mf][nf][reg];
            }
        }
    }
}

// ---------------------------------------------------------------------------
extern "C" void kernel_launch(void* const* d_in, const int* in_sizes, int n_in,
                              void* d_out, int out_size, void* d_ws, size_t ws_size,
                              hipStream_t stream)
{
    (void)in_sizes; (void)n_in; (void)out_size;
    const float* x  = (const float*)d_in[0];
    const float* cl = (const float*)d_in[1];
    const float* W  = (const float*)d_in[2];
    const float* sL = (const float*)d_in[3];
    const float* sR = (const float*)d_in[4];
    float* out = (float*)d_out;

    // ws: A' (64MiB) | Wt (32MiB) | clb (1MiB) | srt (0.5MiB)
    const size_t AP_BYTES = (size_t)BB * DIN * sizeof(bf16);
    const size_t WT_BYTES = (size_t)DIN * DOUT * sizeof(bf16);
    const size_t CL_BYTES = (size_t)BB * NCL * sizeof(bf16);
    const size_t SR_BYTES = (size_t)DOUT * NCL * sizeof(bf16);
    if (ws_size < AP_BYTES + WT_BYTES + CL_BYTES + SR_BYTES) return;

    char* ws = (char*)d_ws;
    bf16* Ap  = (bf16*)ws;
    bf16* Wt  = (bf16*)(ws + AP_BYTES);
    bf16* clb = (bf16*)(ws + AP_BYTES + WT_BYTES);
    bf16* srt = (bf16*)(ws + AP_BYTES + WT_BYTES + CL_BYTES);

    prologue_kernel<<<dim3(BB / 128, DIN / 128), 256, 0, stream>>>(x, cl, sL, Ap, clb);
    transpose_kernel<<<dim3(DOUT / 256, DIN / 32), 256, 0, stream>>>(W, Wt);
    srt_kernel<<<dim3(DOUT / 256), 256, 0, stream>>>(sR, srt);
    gemm_kernel<<<dim3((BB / 256) * (DOUT / 256)), 512, 0, stream>>>(Ap, Wt, clb, srt, out);
}

// Round 7
// 320.848 us; speedup vs baseline: 1.2013x; 1.1389x over previous
//
#include <hip/hip_runtime.h>
#include <cstdint>

// Problem constants (from reference): B=8192, DIN=DOUT=4096, NC=64
#define BB   8192
#define DIN  4096
#define DOUT 4096
#define NCL  64

typedef __bf16 bf16;
typedef __attribute__((ext_vector_type(8))) __bf16 bf16x8;
typedef __attribute__((ext_vector_type(4))) float   f32x4;

#define GAS(p) (reinterpret_cast<uint32_t __attribute__((address_space(1)))*>(reinterpret_cast<uintptr_t>(p)))
#define LAS(p) (reinterpret_cast<uint32_t __attribute__((address_space(3)))*>(reinterpret_cast<uintptr_t>(p)))

#define WAITV(n)  asm volatile("s_waitcnt vmcnt(" #n ")" ::: "memory")
#define WAITL()   asm volatile("s_waitcnt lgkmcnt(0)" ::: "memory")
#define BARR()    __builtin_amdgcn_s_barrier()
#define SCHED0()  __builtin_amdgcn_sched_barrier(0)
#define MFMA(a, b, c) __builtin_amdgcn_mfma_f32_16x16x32_bf16((a), (b), (c), 0, 0, 0)

// ---------------------------------------------------------------------------
// Kernel 1: prologue. tmpL = cluster @ style_L (K=64 MFMA); A' = bf16(x*tmpL).
// v2: epilogue bounces tmpL through LDS so the x-read / Ap-write streams are
// fully coalesced (512B/quarter-wave) instead of 32B strided segments.
// blockIdx.y==0 blocks also dump the cluster tile as bf16 for the GEMM.
// ---------------------------------------------------------------------------
__global__ __launch_bounds__(256) void prologue_kernel(
    const float* __restrict__ x, const float* __restrict__ cl,
    const float* __restrict__ sL, bf16* __restrict__ Ap,
    bf16* __restrict__ clb)
{
    __shared__ char lds[34816]; // 32KB staging, then reused as 128x136 bf16 bounce
    const int t    = threadIdx.x;
    const int lane = t & 63;
    const int w    = t >> 6;
    const int wm   = w >> 1, wn = w & 1;
    const int r0   = blockIdx.x * 128;
    const int c0   = blockIdx.y * 128;

    // stage cluster tile (128x64 f32 -> bf16), swizzled
    #pragma unroll
    for (int i = 0; i < 4; i++) {
        int tk  = t + i * 256;
        int row = tk >> 3, ch = tk & 7;
        const float* src = cl + (size_t)(r0 + row) * NCL + ch * 8;
        float4 v0 = *(const float4*)src;
        float4 v1 = *(const float4*)(src + 4);
        bf16x8 pk;
        pk[0]=(bf16)v0.x; pk[1]=(bf16)v0.y; pk[2]=(bf16)v0.z; pk[3]=(bf16)v0.w;
        pk[4]=(bf16)v1.x; pk[5]=(bf16)v1.y; pk[6]=(bf16)v1.z; pk[7]=(bf16)v1.w;
        *(bf16x8*)(lds + row * 128 + ((ch ^ (row & 7)) << 4)) = pk;
        if (blockIdx.y == 0)
            *(bf16x8*)(clb + (size_t)(r0 + row) * NCL + ch * 8) = pk;
    }
    // stage style_L tile transposed: SL[n][k] = style_L[k][c0+n]
    #pragma unroll
    for (int i = 0; i < 4; i++) {
        int tk = t + i * 256;
        int n  = tk & 127, c = tk >> 7;
        bf16x8 pl;
        #pragma unroll
        for (int j = 0; j < 8; j++)
            pl[j] = (bf16)sL[(size_t)(c * 8 + j) * DIN + c0 + n];
        *(bf16x8*)(lds + 16384 + n * 128 + ((c ^ (n & 7)) << 4)) = pl;
    }
    __syncthreads();

    f32x4 accL[4][4] = {};
    #pragma unroll
    for (int s = 0; s < 2; s++) {
        bf16x8 a[4], bl[4];
        #pragma unroll
        for (int m = 0; m < 4; m++) {
            int row = wm * 64 + m * 16 + (lane & 15);
            int ch  = s * 4 + (lane >> 4);
            a[m] = *(bf16x8*)(lds + row * 128 + ((ch ^ (row & 7)) << 4));
        }
        #pragma unroll
        for (int n = 0; n < 4; n++) {
            int row = wn * 64 + n * 16 + (lane & 15);
            int ch  = s * 4 + (lane >> 4);
            bl[n] = *(bf16x8*)(lds + 16384 + row * 128 + ((ch ^ (row & 7)) << 4));
        }
        #pragma unroll
        for (int m = 0; m < 4; m++)
            #pragma unroll
            for (int n = 0; n < 4; n++)
                accL[m][n] = MFMA(a[m], bl[n], accL[m][n]);
    }
    __syncthreads();   // staging LDS dead; reuse as bounce buffer

    // scatter tmpL (bf16) -> LDS [128 rows][136 cols] (272B rows, b128-aligned)
    #pragma unroll
    for (int m = 0; m < 4; m++) {
        int rbase = wm * 64 + m * 16 + ((lane >> 4) << 2);
        #pragma unroll
        for (int n = 0; n < 4; n++) {
            int col = wn * 64 + n * 16 + (lane & 15);
            #pragma unroll
            for (int j = 0; j < 4; j++)
                *(bf16*)(lds + (rbase + j) * 272 + col * 2) = (bf16)accL[m][n][j];
        }
    }
    __syncthreads();

    // coalesced pass: Ap = bf16(x * tmpL); quarter-wave = one row, 512B x-read
    const int L = t & 15, H = (t >> 4) & 3;
    #pragma unroll
    for (int it = 0; it < 8; it++) {
        int row = it * 16 + w * 4 + H;
        bf16x8 tl = *(const bf16x8*)(lds + row * 272 + L * 16);
        const float* xs = x + (size_t)(r0 + row) * DIN + c0 + L * 8;
        float4 x0 = *(const float4*)xs;
        float4 x1 = *(const float4*)(xs + 4);
        bf16x8 o;
        o[0]=(bf16)(x0.x*(float)tl[0]); o[1]=(bf16)(x0.y*(float)tl[1]);
        o[2]=(bf16)(x0.z*(float)tl[2]); o[3]=(bf16)(x0.w*(float)tl[3]);
        o[4]=(bf16)(x1.x*(float)tl[4]); o[5]=(bf16)(x1.y*(float)tl[5]);
        o[6]=(bf16)(x1.z*(float)tl[6]); o[7]=(bf16)(x1.w*(float)tl[7]);
        *(bf16x8*)(Ap + (size_t)(r0 + row) * DIN + c0 + L * 8) = o;
    }
}

// ---------------------------------------------------------------------------
// Kernel 2: W (DIN x DOUT f32) -> Wt (DOUT x DIN bf16)
// ---------------------------------------------------------------------------
__global__ __launch_bounds__(256) void transpose_kernel(
    const float* __restrict__ W, bf16* __restrict__ Wt)
{
    const int t  = threadIdx.x;
    const int n  = blockIdx.x * 256 + t;
    const int k0 = blockIdx.y * 32;
    bf16x8 v[4];
    #pragma unroll
    for (int q = 0; q < 4; q++)
        #pragma unroll
        for (int j = 0; j < 8; j++)
            v[q][j] = (bf16)W[(size_t)(k0 + q * 8 + j) * DOUT + n];
    bf16* dst = Wt + (size_t)n * DIN + k0;
    #pragma unroll
    for (int q = 0; q < 4; q++)
        *(bf16x8*)(dst + q * 8) = v[q];
}

// ---------------------------------------------------------------------------
// Kernel 2b: style_R (64 x DOUT f32) -> sRt (DOUT x 64 bf16)
// ---------------------------------------------------------------------------
__global__ __launch_bounds__(256) void srt_kernel(
    const float* __restrict__ sR, bf16* __restrict__ srt)
{
    const int o = blockIdx.x * 256 + threadIdx.x;
    bf16x8 v[8];
    #pragma unroll
    for (int q = 0; q < 8; q++)
        #pragma unroll
        for (int j = 0; j < 8; j++)
            v[q][j] = (bf16)sR[(size_t)(q * 8 + j) * DOUT + o];
    bf16* dst = srt + (size_t)o * 64;
    #pragma unroll
    for (int q = 0; q < 8; q++)
        *(bf16x8*)(dst + q * 8) = v[q];
}

// ---------------------------------------------------------------------------
// Kernel 3: 256x256-tile 8-phase GEMM, 16x16x32 MFMA (R4-proven schedule)
// with m201 read-balance 12/4/8/0 and fused tmpR. Per K-tile t:
//   P1: ds_read a0(8)+b01(4); stage (t+1).Ah1->OB; BAR; lgkm0; 16 MFMA; BAR
//   P2: ds_read b23(4);       stage (t+2).Bh0->CB; BAR; lgkm0; 16 MFMA; BAR
//   P3: ds_read a1(8);        stage (t+2).Bh1->CB; BAR; lgkm0; 16 MFMA; BAR
//   P4: (no reads)            stage (t+2).Ah0->CB; BAR; 16 MFMA; vmcnt(6); BAR
// Slot-death audit: every piece's reads drain at that phase's lgkm0 (before
// its end-barrier), >=1 barrier before any re-stage of the same slots.
// ---------------------------------------------------------------------------
template<int CUR>
__device__ __forceinline__ void tile_step(char* lds, int tid,
    const bf16* pA1, const bf16* pA2, const bf16* pA3, const bf16* pA4,
    const bf16* pB1, const bf16* pB2, const bf16* pB3, const bf16* pB4,
    int kA1, int kA2, int aoff0, int aoff1, int boff0, int boff1,
    bf16x8 a[4][2], bf16x8 b[4][2], f32x4 acc[8][4])
{
    constexpr int CB = CUR * 65536;
    constexpr int OB = (CUR ^ 1) * 65536;

    // ---------- P1 ----------
    #pragma unroll
    for (int mq = 0; mq < 4; ++mq) {
        a[mq][0] = *(const bf16x8*)(lds + CB + mq * 2048 + aoff0);
        a[mq][1] = *(const bf16x8*)(lds + CB + mq * 2048 + aoff1);
    }
    #pragma unroll
    for (int nb = 0; nb < 2; ++nb) {
        b[nb][0] = *(const bf16x8*)(lds + CB + nb * 2048 + boff0);
        b[nb][1] = *(const bf16x8*)(lds + CB + nb * 2048 + boff1);
    }
    __builtin_amdgcn_global_load_lds(GAS(pA3 + kA1), LAS(lds + OB + 16384 + tid * 16), 16, 0, 0);
    __builtin_amdgcn_global_load_lds(GAS(pA4 + kA1), LAS(lds + OB + 24576 + tid * 16), 16, 0, 0);
    BARR();
    WAITL(); SCHED0();
    __builtin_amdgcn_s_setprio(1);
    #pragma unroll
    for (int k = 0; k < 2; ++k)
        #pragma unroll
        for (int mq = 0; mq < 4; ++mq)
            #pragma unroll
            for (int nq = 0; nq < 2; ++nq)
                acc[mq][nq] = MFMA(a[mq][k], b[nq][k], acc[mq][nq]);
    __builtin_amdgcn_s_setprio(0);
    BARR();

    // ---------- P2 ----------
    #pragma unroll
    for (int nb = 2; nb < 4; ++nb) {
        b[nb][0] = *(const bf16x8*)(lds + CB + nb * 2048 + boff0);
        b[nb][1] = *(const bf16x8*)(lds + CB + nb * 2048 + boff1);
    }
    __builtin_amdgcn_global_load_lds(GAS(pB1 + kA2), LAS(lds + CB + 32768 + tid * 16), 16, 0, 0);
    __builtin_amdgcn_global_load_lds(GAS(pB2 + kA2), LAS(lds + CB + 40960 + tid * 16), 16, 0, 0);
    BARR();
    WAITL(); SCHED0();
    __builtin_amdgcn_s_setprio(1);
    #pragma unroll
    for (int k = 0; k < 2; ++k)
        #pragma unroll
        for (int mq = 0; mq < 4; ++mq)
            #pragma unroll
            for (int nq = 0; nq < 2; ++nq)
                acc[mq][2 + nq] = MFMA(a[mq][k], b[2 + nq][k], acc[mq][2 + nq]);
    __builtin_amdgcn_s_setprio(0);
    BARR();

    // ---------- P3 ----------
    #pragma unroll
    for (int mq = 0; mq < 4; ++mq) {
        a[mq][0] = *(const bf16x8*)(lds + CB + 8192 + mq * 2048 + aoff0);
        a[mq][1] = *(const bf16x8*)(lds + CB + 8192 + mq * 2048 + aoff1);
    }
    __builtin_amdgcn_global_load_lds(GAS(pB3 + kA2), LAS(lds + CB + 49152 + tid * 16), 16, 0, 0);
    __builtin_amdgcn_global_load_lds(GAS(pB4 + kA2), LAS(lds + CB + 57344 + tid * 16), 16, 0, 0);
    BARR();
    WAITL(); SCHED0();
    __builtin_amdgcn_s_setprio(1);
    #pragma unroll
    for (int k = 0; k < 2; ++k)
        #pragma unroll
        for (int mq = 0; mq < 4; ++mq)
            #pragma unroll
            for (int nq = 0; nq < 2; ++nq)
                acc[4 + mq][2 + nq] = MFMA(a[mq][k], b[2 + nq][k], acc[4 + mq][2 + nq]);
    __builtin_amdgcn_s_setprio(0);
    BARR();

    // ---------- P4 ----------
    __builtin_amdgcn_global_load_lds(GAS(pA1 + kA2), LAS(lds + CB + tid * 16), 16, 0, 0);
    __builtin_amdgcn_global_load_lds(GAS(pA2 + kA2), LAS(lds + CB + 8192 + tid * 16), 16, 0, 0);
    BARR();
    __builtin_amdgcn_s_setprio(1);
    #pragma unroll
    for (int k = 0; k < 2; ++k)
        #pragma unroll
        for (int mq = 0; mq < 4; ++mq)
            #pragma unroll
            for (int nq = 0; nq < 2; ++nq)
                acc[4 + mq][nq] = MFMA(a[mq][k], b[nq][k], acc[4 + mq][nq]);
    __builtin_amdgcn_s_setprio(0);
    WAITV(6);
    BARR();
}

__global__ __launch_bounds__(512, 2) void gemm_kernel(
    const bf16* __restrict__ Ap, const bf16* __restrict__ Wt,
    const bf16* __restrict__ clb, const bf16* __restrict__ srt,
    float* __restrict__ out)
{
    __shared__ uint4 smem[8192]; // 128 KiB
    char* lds = (char*)smem;
    const int tid  = threadIdx.x;
    const int lane = tid & 63;
    const int w    = tid >> 6;
    const int wm   = w >> 2;   // 0..1
    const int wn   = w & 3;    // 0..3
    const int L = lane & 15, H = lane >> 4;

    // XCD-bijective swizzle, 8x8 tile block per XCD (better L2 footprint):
    // 512 blocks, 8 XCDs, 64 tiles each.
    const int bid = blockIdx.x;
    const int xc  = bid & 7, ii = bid >> 3;
    const int mt  = (xc >> 1) * 8 + (ii >> 3);
    const int nt  = (xc & 1) * 8 + (ii & 7);
    const size_t brow = (size_t)mt * 256;
    const size_t bcol = (size_t)nt * 256;

    // staging: dest linear (tid*16), source chunk inverse-swizzled
    const int r1  = tid >> 3;
    const int gch = (tid & 7) ^ (r1 & 7);
    const bf16* pA1 = Ap + (brow + r1) * (size_t)DIN + gch * 8;
    const bf16* pA2 = pA1 + (size_t)64  * DIN;
    const bf16* pA3 = pA1 + (size_t)128 * DIN;
    const bf16* pA4 = pA1 + (size_t)192 * DIN;
    const bf16* pB1 = Wt + (bcol + r1) * (size_t)DIN + gch * 8;
    const bf16* pB2 = pB1 + (size_t)64  * DIN;
    const bf16* pB3 = pB1 + (size_t)128 * DIN;
    const bf16* pB4 = pB1 + (size_t)192 * DIN;

    // fragment ds_read offsets: chunk = kk*4+H, slot = chunk^(L&7)
    const int swz0 = (H ^ (L & 7)) << 4;
    const int swz1 = ((4 + H) ^ (L & 7)) << 4;
    const int aoff0 = wm * 16384 + L * 128 + swz0;
    const int aoff1 = wm * 16384 + L * 128 + swz1;
    const int boff0 = 32768 + (wn >> 1) * 16384 + (wn & 1) * 8192 + L * 128 + swz0;
    const int boff1 = 32768 + (wn >> 1) * 16384 + (wn & 1) * 8192 + L * 128 + swz1;

    bf16x8 a[4][2], b[4][2];
    f32x4 acc[8][4] = {};

    // prologue: tile0 all 4 pieces -> buf0; tile1 {Bh0,Bh1,Ah0} -> buf1
    __builtin_amdgcn_global_load_lds(GAS(pA1), LAS(lds + tid * 16), 16, 0, 0);
    __builtin_amdgcn_global_load_lds(GAS(pA2), LAS(lds + 8192 + tid * 16), 16, 0, 0);
    __builtin_amdgcn_global_load_lds(GAS(pA3), LAS(lds + 16384 + tid * 16), 16, 0, 0);
    __builtin_amdgcn_global_load_lds(GAS(pA4), LAS(lds + 24576 + tid * 16), 16, 0, 0);
    __builtin_amdgcn_global_load_lds(GAS(pB1), LAS(lds + 32768 + tid * 16), 16, 0, 0);
    __builtin_amdgcn_global_load_lds(GAS(pB2), LAS(lds + 40960 + tid * 16), 16, 0, 0);
    __builtin_amdgcn_global_load_lds(GAS(pB3), LAS(lds + 49152 + tid * 16), 16, 0, 0);
    __builtin_amdgcn_global_load_lds(GAS(pB4), LAS(lds + 57344 + tid * 16), 16, 0, 0);
    __builtin_amdgcn_global_load_lds(GAS(pB1 + 64), LAS(lds + 65536 + 32768 + tid * 16), 16, 0, 0);
    __builtin_amdgcn_global_load_lds(GAS(pB2 + 64), LAS(lds + 65536 + 40960 + tid * 16), 16, 0, 0);
    __builtin_amdgcn_global_load_lds(GAS(pB3 + 64), LAS(lds + 65536 + 49152 + tid * 16), 16, 0, 0);
    __builtin_amdgcn_global_load_lds(GAS(pB4 + 64), LAS(lds + 65536 + 57344 + tid * 16), 16, 0, 0);
    __builtin_amdgcn_global_load_lds(GAS(pA1 + 64), LAS(lds + 65536 + tid * 16), 16, 0, 0);
    __builtin_amdgcn_global_load_lds(GAS(pA2 + 64), LAS(lds + 65536 + 8192 + tid * 16), 16, 0, 0);
    WAITV(6);
    BARR();

    #pragma unroll 1
    for (int t = 0; t < 64; t += 2) {
        tile_step<0>(lds, tid, pA1, pA2, pA3, pA4, pB1, pB2, pB3, pB4,
                     ((t + 1) & 63) * 64, ((t + 2) & 63) * 64,
                     aoff0, aoff1, boff0, boff1, a, b, acc);
        tile_step<1>(lds, tid, pA1, pA2, pA3, pA4, pB1, pB2, pB3, pB4,
                     ((t + 2) & 63) * 64, ((t + 3) & 63) * 64,
                     aoff0, aoff1, boff0, boff1, a, b, acc);
    }

    // ---- fused tmpR tile: acc *= (cluster @ style_R) over K=64 ----
    WAITV(0);                    // drain wrap-around junk prefetches
    const bf16* pC = clb + (brow + r1) * 64 + gch * 8;
    const bf16* pR = srt + (bcol + r1) * 64 + gch * 8;
    __builtin_amdgcn_global_load_lds(GAS(pC),         LAS(lds + tid * 16), 16, 0, 0);
    __builtin_amdgcn_global_load_lds(GAS(pC + 4096),  LAS(lds + 8192 + tid * 16), 16, 0, 0);
    __builtin_amdgcn_global_load_lds(GAS(pC + 8192),  LAS(lds + 16384 + tid * 16), 16, 0, 0);
    __builtin_amdgcn_global_load_lds(GAS(pC + 12288), LAS(lds + 24576 + tid * 16), 16, 0, 0);
    __builtin_amdgcn_global_load_lds(GAS(pR),         LAS(lds + 32768 + tid * 16), 16, 0, 0);
    __builtin_amdgcn_global_load_lds(GAS(pR + 4096),  LAS(lds + 40960 + tid * 16), 16, 0, 0);
    __builtin_amdgcn_global_load_lds(GAS(pR + 8192),  LAS(lds + 49152 + tid * 16), 16, 0, 0);
    __builtin_amdgcn_global_load_lds(GAS(pR + 12288), LAS(lds + 57344 + tid * 16), 16, 0, 0);
    WAITV(0);
    BARR();

    #pragma unroll
    for (int nb = 0; nb < 4; ++nb) {
        b[nb][0] = *(const bf16x8*)(lds + nb * 2048 + boff0);
        b[nb][1] = *(const bf16x8*)(lds + nb * 2048 + boff1);
    }
    #pragma unroll
    for (int half = 0; half < 2; ++half) {
        #pragma unroll
        for (int mq = 0; mq < 4; ++mq) {
            a[mq][0] = *(const bf16x8*)(lds + half * 8192 + mq * 2048 + aoff0);
            a[mq][1] = *(const bf16x8*)(lds + half * 8192 + mq * 2048 + aoff1);
        }
        WAITL(); SCHED0();
        f32x4 r4[4][4] = {};
        #pragma unroll
        for (int k = 0; k < 2; ++k)
            #pragma unroll
            for (int mq = 0; mq < 4; ++mq)
                #pragma unroll
                for (int nb = 0; nb < 4; ++nb)
                    r4[mq][nb] = MFMA(a[mq][k], b[nb][k], r4[mq][nb]);
        #pragma unroll
        for (int mq = 0; mq < 4; ++mq)
            #pragma unroll
            for (int nb = 0; nb < 4; ++nb)
                acc[half * 4 + mq][nb] *= r4[mq][nb];
    }

    // epilogue: out = acc (already modulated), f32 stores
    #pragma unroll
    for (int m = 0; m < 8; m++) {
        size_t rbase = brow + (size_t)(wm * 128 + m * 16 + (H << 2));
        #pragma unroll
        for (int n = 0; n < 4; n++) {
            size_t col = bcol + (size_t)(wn * 64 + n * 16 + L);
            #pragma unroll
            for (int j = 0; j < 4; j++) {
                size_t idx = (rbase + j) * DOUT + col;
                out[idx] = acc[m][n][j];
            }
        }
    }
}

// ---------------------------------------------------------------------------
extern "C" void kernel_launch(void* const* d_in, const int* in_sizes, int n_in,
                              void* d_out, int out_size, void* d_ws, size_t ws_size,
                              hipStream_t stream)
{
    (void)in_sizes; (void)n_in; (void)out_size;
    const float* x  = (const float*)d_in[0];
    const float* cl = (const float*)d_in[1];
    const float* W  = (const float*)d_in[2];
    const float* sL = (const float*)d_in[3];
    const float* sR = (const float*)d_in[4];
    float* out = (float*)d_out;

    // ws: A' (64MiB) | Wt (32MiB) | clb (1MiB) | srt (0.5MiB)
    const size_t AP_BYTES = (size_t)BB * DIN * sizeof(bf16);
    const size_t WT_BYTES = (size_t)DIN * DOUT * sizeof(bf16);
    const size_t CL_BYTES = (size_t)BB * NCL * sizeof(bf16);
    const size_t SR_BYTES = (size_t)DOUT * NCL * sizeof(bf16);
    if (ws_size < AP_BYTES + WT_BYTES + CL_BYTES + SR_BYTES) return;

    char* ws = (char*)d_ws;
    bf16* Ap  = (bf16*)ws;
    bf16* Wt  = (bf16*)(ws + AP_BYTES);
    bf16* clb = (bf16*)(ws + AP_BYTES + WT_BYTES);
    bf16* srt = (bf16*)(ws + AP_BYTES + WT_BYTES + CL_BYTES);

    prologue_kernel<<<dim3(BB / 128, DIN / 128), 256, 0, stream>>>(x, cl, sL, Ap, clb);
    transpose_kernel<<<dim3(DOUT / 256, DIN / 32), 256, 0, stream>>>(W, Wt);
    srt_kernel<<<dim3(DOUT / 256), 256, 0, stream>>>(sR, srt);
    gemm_kernel<<<dim3((BB / 256) * (DOUT / 256)), 512, 0, stream>>>(Ap, Wt, clb, srt, out);
}

// Round 8
// 309.679 us; speedup vs baseline: 1.2446x; 1.0361x over previous
//
#include <hip/hip_runtime.h>
#include <cstdint>

// Problem constants (from reference): B=8192, DIN=DOUT=4096, NC=64
#define BB   8192
#define DIN  4096
#define DOUT 4096
#define NCL  64

typedef __bf16 bf16;
typedef __attribute__((ext_vector_type(8))) __bf16 bf16x8;
typedef __attribute__((ext_vector_type(4))) float   f32x4;

#define GAS(p) (reinterpret_cast<uint32_t __attribute__((address_space(1)))*>(reinterpret_cast<uintptr_t>(p)))
#define LAS(p) (reinterpret_cast<uint32_t __attribute__((address_space(3)))*>(reinterpret_cast<uintptr_t>(p)))

#define WAITV(n)  asm volatile("s_waitcnt vmcnt(" #n ")" ::: "memory")
#define WAITL()   asm volatile("s_waitcnt lgkmcnt(0)" ::: "memory")
#define BARR()    __builtin_amdgcn_s_barrier()
#define SCHED0()  __builtin_amdgcn_sched_barrier(0)
#define MFMA(a, b, c) __builtin_amdgcn_mfma_f32_16x16x32_bf16((a), (b), (c), 0, 0, 0)

// ---------------------------------------------------------------------------
// Kernel 1: prologue (R7-proven). tmpL = cluster @ style_L (K=64 MFMA);
// A' = bf16(x*tmpL) written via LDS bounce for fully-coalesced x/Ap streams.
// blockIdx.y==0 blocks also dump the cluster tile as bf16 for the GEMM.
// ---------------------------------------------------------------------------
__global__ __launch_bounds__(256) void prologue_kernel(
    const float* __restrict__ x, const float* __restrict__ cl,
    const float* __restrict__ sL, bf16* __restrict__ Ap,
    bf16* __restrict__ clb)
{
    __shared__ char lds[34816]; // 32KB staging, then reused as 128x136 bf16 bounce
    const int t    = threadIdx.x;
    const int lane = t & 63;
    const int w    = t >> 6;
    const int wm   = w >> 1, wn = w & 1;
    const int r0   = blockIdx.x * 128;
    const int c0   = blockIdx.y * 128;

    // stage cluster tile (128x64 f32 -> bf16), swizzled
    #pragma unroll
    for (int i = 0; i < 4; i++) {
        int tk  = t + i * 256;
        int row = tk >> 3, ch = tk & 7;
        const float* src = cl + (size_t)(r0 + row) * NCL + ch * 8;
        float4 v0 = *(const float4*)src;
        float4 v1 = *(const float4*)(src + 4);
        bf16x8 pk;
        pk[0]=(bf16)v0.x; pk[1]=(bf16)v0.y; pk[2]=(bf16)v0.z; pk[3]=(bf16)v0.w;
        pk[4]=(bf16)v1.x; pk[5]=(bf16)v1.y; pk[6]=(bf16)v1.z; pk[7]=(bf16)v1.w;
        *(bf16x8*)(lds + row * 128 + ((ch ^ (row & 7)) << 4)) = pk;
        if (blockIdx.y == 0)
            *(bf16x8*)(clb + (size_t)(r0 + row) * NCL + ch * 8) = pk;
    }
    // stage style_L tile transposed: SL[n][k] = style_L[k][c0+n]
    #pragma unroll
    for (int i = 0; i < 4; i++) {
        int tk = t + i * 256;
        int n  = tk & 127, c = tk >> 7;
        bf16x8 pl;
        #pragma unroll
        for (int j = 0; j < 8; j++)
            pl[j] = (bf16)sL[(size_t)(c * 8 + j) * DIN + c0 + n];
        *(bf16x8*)(lds + 16384 + n * 128 + ((c ^ (n & 7)) << 4)) = pl;
    }
    __syncthreads();

    f32x4 accL[4][4] = {};
    #pragma unroll
    for (int s = 0; s < 2; s++) {
        bf16x8 a[4], bl[4];
        #pragma unroll
        for (int m = 0; m < 4; m++) {
            int row = wm * 64 + m * 16 + (lane & 15);
            int ch  = s * 4 + (lane >> 4);
            a[m] = *(bf16x8*)(lds + row * 128 + ((ch ^ (row & 7)) << 4));
        }
        #pragma unroll
        for (int n = 0; n < 4; n++) {
            int row = wn * 64 + n * 16 + (lane & 15);
            int ch  = s * 4 + (lane >> 4);
            bl[n] = *(bf16x8*)(lds + 16384 + row * 128 + ((ch ^ (row & 7)) << 4));
        }
        #pragma unroll
        for (int m = 0; m < 4; m++)
            #pragma unroll
            for (int n = 0; n < 4; n++)
                accL[m][n] = MFMA(a[m], bl[n], accL[m][n]);
    }
    __syncthreads();   // staging LDS dead; reuse as bounce buffer

    // scatter tmpL (bf16) -> LDS [128 rows][136 cols]
    #pragma unroll
    for (int m = 0; m < 4; m++) {
        int rbase = wm * 64 + m * 16 + ((lane >> 4) << 2);
        #pragma unroll
        for (int n = 0; n < 4; n++) {
            int col = wn * 64 + n * 16 + (lane & 15);
            #pragma unroll
            for (int j = 0; j < 4; j++)
                *(bf16*)(lds + (rbase + j) * 272 + col * 2) = (bf16)accL[m][n][j];
        }
    }
    __syncthreads();

    // coalesced pass: Ap = bf16(x * tmpL); quarter-wave = one row, 512B x-read
    const int L = t & 15, H = (t >> 4) & 3;
    #pragma unroll
    for (int it = 0; it < 8; it++) {
        int row = it * 16 + w * 4 + H;
        bf16x8 tl = *(const bf16x8*)(lds + row * 272 + L * 16);
        const float* xs = x + (size_t)(r0 + row) * DIN + c0 + L * 8;
        float4 x0 = *(const float4*)xs;
        float4 x1 = *(const float4*)(xs + 4);
        bf16x8 o;
        o[0]=(bf16)(x0.x*(float)tl[0]); o[1]=(bf16)(x0.y*(float)tl[1]);
        o[2]=(bf16)(x0.z*(float)tl[2]); o[3]=(bf16)(x0.w*(float)tl[3]);
        o[4]=(bf16)(x1.x*(float)tl[4]); o[5]=(bf16)(x1.y*(float)tl[5]);
        o[6]=(bf16)(x1.z*(float)tl[6]); o[7]=(bf16)(x1.w*(float)tl[7]);
        *(bf16x8*)(Ap + (size_t)(r0 + row) * DIN + c0 + L * 8) = o;
    }
}

// ---------------------------------------------------------------------------
// Kernel 2 (fused streaming prep): block-range dispatch, no LDS, low regs.
//   blocks [0,2048):    W (DIN x DOUT f32) -> Wt (DOUT x DIN bf16)
//   blocks [2048,2064): style_R (64 x DOUT f32) -> sRt (DOUT x 64 bf16)
// ---------------------------------------------------------------------------
__global__ __launch_bounds__(256) void wprep_kernel(
    const float* __restrict__ W, const float* __restrict__ sR,
    bf16* __restrict__ Wt, bf16* __restrict__ srt)
{
    const int bid = blockIdx.x;
    const int t   = threadIdx.x;
    if (bid < 2048) {
        const int n  = (bid & 15) * 256 + t;
        const int k0 = (bid >> 4) * 32;
        bf16x8 v[4];
        #pragma unroll
        for (int q = 0; q < 4; q++)
            #pragma unroll
            for (int j = 0; j < 8; j++)
                v[q][j] = (bf16)W[(size_t)(k0 + q * 8 + j) * DOUT + n];
        bf16* dst = Wt + (size_t)n * DIN + k0;
        #pragma unroll
        for (int q = 0; q < 4; q++)
            *(bf16x8*)(dst + q * 8) = v[q];
    } else {
        const int o = (bid - 2048) * 256 + t;
        bf16x8 v[8];
        #pragma unroll
        for (int q = 0; q < 8; q++)
            #pragma unroll
            for (int j = 0; j < 8; j++)
                v[q][j] = (bf16)sR[(size_t)(q * 8 + j) * DOUT + o];
        bf16* dst = srt + (size_t)o * 64;
        #pragma unroll
        for (int q = 0; q < 8; q++)
            *(bf16x8*)(dst + q * 8) = v[q];
    }
}

// ---------------------------------------------------------------------------
// Kernel 3: 256x256-tile 8-phase GEMM, 16x16x32 MFMA (R7-proven schedule,
// read-balance 12/4/8/0, fused tmpR, XCD 8x8 mapping). UNCHANGED from R7.
// ---------------------------------------------------------------------------
template<int CUR>
__device__ __forceinline__ void tile_step(char* lds, int tid,
    const bf16* pA1, const bf16* pA2, const bf16* pA3, const bf16* pA4,
    const bf16* pB1, const bf16* pB2, const bf16* pB3, const bf16* pB4,
    int kA1, int kA2, int aoff0, int aoff1, int boff0, int boff1,
    bf16x8 a[4][2], bf16x8 b[4][2], f32x4 acc[8][4])
{
    constexpr int CB = CUR * 65536;
    constexpr int OB = (CUR ^ 1) * 65536;

    // ---------- P1 ----------
    #pragma unroll
    for (int mq = 0; mq < 4; ++mq) {
        a[mq][0] = *(const bf16x8*)(lds + CB + mq * 2048 + aoff0);
        a[mq][1] = *(const bf16x8*)(lds + CB + mq * 2048 + aoff1);
    }
    #pragma unroll
    for (int nb = 0; nb < 2; ++nb) {
        b[nb][0] = *(const bf16x8*)(lds + CB + nb * 2048 + boff0);
        b[nb][1] = *(const bf16x8*)(lds + CB + nb * 2048 + boff1);
    }
    __builtin_amdgcn_global_load_lds(GAS(pA3 + kA1), LAS(lds + OB + 16384 + tid * 16), 16, 0, 0);
    __builtin_amdgcn_global_load_lds(GAS(pA4 + kA1), LAS(lds + OB + 24576 + tid * 16), 16, 0, 0);
    BARR();
    WAITL(); SCHED0();
    __builtin_amdgcn_s_setprio(1);
    #pragma unroll
    for (int k = 0; k < 2; ++k)
        #pragma unroll
        for (int mq = 0; mq < 4; ++mq)
            #pragma unroll
            for (int nq = 0; nq < 2; ++nq)
                acc[mq][nq] = MFMA(a[mq][k], b[nq][k], acc[mq][nq]);
    __builtin_amdgcn_s_setprio(0);
    BARR();

    // ---------- P2 ----------
    #pragma unroll
    for (int nb = 2; nb < 4; ++nb) {
        b[nb][0] = *(const bf16x8*)(lds + CB + nb * 2048 + boff0);
        b[nb][1] = *(const bf16x8*)(lds + CB + nb * 2048 + boff1);
    }
    __builtin_amdgcn_global_load_lds(GAS(pB1 + kA2), LAS(lds + CB + 32768 + tid * 16), 16, 0, 0);
    __builtin_amdgcn_global_load_lds(GAS(pB2 + kA2), LAS(lds + CB + 40960 + tid * 16), 16, 0, 0);
    BARR();
    WAITL(); SCHED0();
    __builtin_amdgcn_s_setprio(1);
    #pragma unroll
    for (int k = 0; k < 2; ++k)
        #pragma unroll
        for (int mq = 0; mq < 4; ++mq)
            #pragma unroll
            for (int nq = 0; nq < 2; ++nq)
                acc[mq][2 + nq] = MFMA(a[mq][k], b[2 + nq][k], acc[mq][2 + nq]);
    __builtin_amdgcn_s_setprio(0);
    BARR();

    // ---------- P3 ----------
    #pragma unroll
    for (int mq = 0; mq < 4; ++mq) {
        a[mq][0] = *(const bf16x8*)(lds + CB + 8192 + mq * 2048 + aoff0);
        a[mq][1] = *(const bf16x8*)(lds + CB + 8192 + mq * 2048 + aoff1);
    }
    __builtin_amdgcn_global_load_lds(GAS(pB3 + kA2), LAS(lds + CB + 49152 + tid * 16), 16, 0, 0);
    __builtin_amdgcn_global_load_lds(GAS(pB4 + kA2), LAS(lds + CB + 57344 + tid * 16), 16, 0, 0);
    BARR();
    WAITL(); SCHED0();
    __builtin_amdgcn_s_setprio(1);
    #pragma unroll
    for (int k = 0; k < 2; ++k)
        #pragma unroll
        for (int mq = 0; mq < 4; ++mq)
            #pragma unroll
            for (int nq = 0; nq < 2; ++nq)
                acc[4 + mq][2 + nq] = MFMA(a[mq][k], b[2 + nq][k], acc[4 + mq][2 + nq]);
    __builtin_amdgcn_s_setprio(0);
    BARR();

    // ---------- P4 ----------
    __builtin_amdgcn_global_load_lds(GAS(pA1 + kA2), LAS(lds + CB + tid * 16), 16, 0, 0);
    __builtin_amdgcn_global_load_lds(GAS(pA2 + kA2), LAS(lds + CB + 8192 + tid * 16), 16, 0, 0);
    BARR();
    __builtin_amdgcn_s_setprio(1);
    #pragma unroll
    for (int k = 0; k < 2; ++k)
        #pragma unroll
        for (int mq = 0; mq < 4; ++mq)
            #pragma unroll
            for (int nq = 0; nq < 2; ++nq)
                acc[4 + mq][nq] = MFMA(a[mq][k], b[nq][k], acc[4 + mq][nq]);
    __builtin_amdgcn_s_setprio(0);
    WAITV(6);
    BARR();
}

__global__ __launch_bounds__(512, 2) void gemm_kernel(
    const bf16* __restrict__ Ap, const bf16* __restrict__ Wt,
    const bf16* __restrict__ clb, const bf16* __restrict__ srt,
    float* __restrict__ out)
{
    __shared__ uint4 smem[8192]; // 128 KiB
    char* lds = (char*)smem;
    const int tid  = threadIdx.x;
    const int lane = tid & 63;
    const int w    = tid >> 6;
    const int wm   = w >> 2;   // 0..1
    const int wn   = w & 3;    // 0..3
    const int L = lane & 15, H = lane >> 4;

    // XCD-bijective swizzle, 8x8 tile block per XCD
    const int bid = blockIdx.x;
    const int xc  = bid & 7, ii = bid >> 3;
    const int mt  = (xc >> 1) * 8 + (ii >> 3);
    const int nt  = (xc & 1) * 8 + (ii & 7);
    const size_t brow = (size_t)mt * 256;
    const size_t bcol = (size_t)nt * 256;

    // staging: dest linear (tid*16), source chunk inverse-swizzled
    const int r1  = tid >> 3;
    const int gch = (tid & 7) ^ (r1 & 7);
    const bf16* pA1 = Ap + (brow + r1) * (size_t)DIN + gch * 8;
    const bf16* pA2 = pA1 + (size_t)64  * DIN;
    const bf16* pA3 = pA1 + (size_t)128 * DIN;
    const bf16* pA4 = pA1 + (size_t)192 * DIN;
    const bf16* pB1 = Wt + (bcol + r1) * (size_t)DIN + gch * 8;
    const bf16* pB2 = pB1 + (size_t)64  * DIN;
    const bf16* pB3 = pB1 + (size_t)128 * DIN;
    const bf16* pB4 = pB1 + (size_t)192 * DIN;

    // fragment ds_read offsets: chunk = kk*4+H, slot = chunk^(L&7)
    const int swz0 = (H ^ (L & 7)) << 4;
    const int swz1 = ((4 + H) ^ (L & 7)) << 4;
    const int aoff0 = wm * 16384 + L * 128 + swz0;
    const int aoff1 = wm * 16384 + L * 128 + swz1;
    const int boff0 = 32768 + (wn >> 1) * 16384 + (wn & 1) * 8192 + L * 128 + swz0;
    const int boff1 = 32768 + (wn >> 1) * 16384 + (wn & 1) * 8192 + L * 128 + swz1;

    bf16x8 a[4][2], b[4][2];
    f32x4 acc[8][4] = {};

    // prologue: tile0 all 4 pieces -> buf0; tile1 {Bh0,Bh1,Ah0} -> buf1
    __builtin_amdgcn_global_load_lds(GAS(pA1), LAS(lds + tid * 16), 16, 0, 0);
    __builtin_amdgcn_global_load_lds(GAS(pA2), LAS(lds + 8192 + tid * 16), 16, 0, 0);
    __builtin_amdgcn_global_load_lds(GAS(pA3), LAS(lds + 16384 + tid * 16), 16, 0, 0);
    __builtin_amdgcn_global_load_lds(GAS(pA4), LAS(lds + 24576 + tid * 16), 16, 0, 0);
    __builtin_amdgcn_global_load_lds(GAS(pB1), LAS(lds + 32768 + tid * 16), 16, 0, 0);
    __builtin_amdgcn_global_load_lds(GAS(pB2), LAS(lds + 40960 + tid * 16), 16, 0, 0);
    __builtin_amdgcn_global_load_lds(GAS(pB3), LAS(lds + 49152 + tid * 16), 16, 0, 0);
    __builtin_amdgcn_global_load_lds(GAS(pB4), LAS(lds + 57344 + tid * 16), 16, 0, 0);
    __builtin_amdgcn_global_load_lds(GAS(pB1 + 64), LAS(lds + 65536 + 32768 + tid * 16), 16, 0, 0);
    __builtin_amdgcn_global_load_lds(GAS(pB2 + 64), LAS(lds + 65536 + 40960 + tid * 16), 16, 0, 0);
    __builtin_amdgcn_global_load_lds(GAS(pB3 + 64), LAS(lds + 65536 + 49152 + tid * 16), 16, 0, 0);
    __builtin_amdgcn_global_load_lds(GAS(pB4 + 64), LAS(lds + 65536 + 57344 + tid * 16), 16, 0, 0);
    __builtin_amdgcn_global_load_lds(GAS(pA1 + 64), LAS(lds + 65536 + tid * 16), 16, 0, 0);
    __builtin_amdgcn_global_load_lds(GAS(pA2 + 64), LAS(lds + 65536 + 8192 + tid * 16), 16, 0, 0);
    WAITV(6);
    BARR();

    #pragma unroll 1
    for (int t = 0; t < 64; t += 2) {
        tile_step<0>(lds, tid, pA1, pA2, pA3, pA4, pB1, pB2, pB3, pB4,
                     ((t + 1) & 63) * 64, ((t + 2) & 63) * 64,
                     aoff0, aoff1, boff0, boff1, a, b, acc);
        tile_step<1>(lds, tid, pA1, pA2, pA3, pA4, pB1, pB2, pB3, pB4,
                     ((t + 2) & 63) * 64, ((t + 3) & 63) * 64,
                     aoff0, aoff1, boff0, boff1, a, b, acc);
    }

    // ---- fused tmpR tile: acc *= (cluster @ style_R) over K=64 ----
    WAITV(0);   // drain wrap-around junk prefetches BEFORE reusing their LDS slots
    const bf16* pC = clb + (brow + r1) * 64 + gch * 8;
    const bf16* pR = srt + (bcol + r1) * 64 + gch * 8;
    __builtin_amdgcn_global_load_lds(GAS(pC),         LAS(lds + tid * 16), 16, 0, 0);
    __builtin_amdgcn_global_load_lds(GAS(pC + 4096),  LAS(lds + 8192 + tid * 16), 16, 0, 0);
    __builtin_amdgcn_global_load_lds(GAS(pC + 8192),  LAS(lds + 16384 + tid * 16), 16, 0, 0);
    __builtin_amdgcn_global_load_lds(GAS(pC + 12288), LAS(lds + 24576 + tid * 16), 16, 0, 0);
    __builtin_amdgcn_global_load_lds(GAS(pR),         LAS(lds + 32768 + tid * 16), 16, 0, 0);
    __builtin_amdgcn_global_load_lds(GAS(pR + 4096),  LAS(lds + 40960 + tid * 16), 16, 0, 0);
    __builtin_amdgcn_global_load_lds(GAS(pR + 8192),  LAS(lds + 49152 + tid * 16), 16, 0, 0);
    __builtin_amdgcn_global_load_lds(GAS(pR + 12288), LAS(lds + 57344 + tid * 16), 16, 0, 0);
    WAITV(0);
    BARR();

    #pragma unroll
    for (int nb = 0; nb < 4; ++nb) {
        b[nb][0] = *(const bf16x8*)(lds + nb * 2048 + boff0);
        b[nb][1] = *(const bf16x8*)(lds + nb * 2048 + boff1);
    }
    #pragma unroll
    for (int half = 0; half < 2; ++half) {
        #pragma unroll
        for (int mq = 0; mq < 4; ++mq) {
            a[mq][0] = *(const bf16x8*)(lds + half * 8192 + mq * 2048 + aoff0);
            a[mq][1] = *(const bf16x8*)(lds + half * 8192 + mq * 2048 + aoff1);
        }
        WAITL(); SCHED0();
        f32x4 r4[4][4] = {};
        #pragma unroll
        for (int k = 0; k < 2; ++k)
            #pragma unroll
            for (int mq = 0; mq < 4; ++mq)
                #pragma unroll
                for (int nb = 0; nb < 4; ++nb)
                    r4[mq][nb] = MFMA(a[mq][k], b[nb][k], r4[mq][nb]);
        #pragma unroll
        for (int mq = 0; mq < 4; ++mq)
            #pragma unroll
            for (int nb = 0; nb < 4; ++nb)
                acc[half * 4 + mq][nb] *= r4[mq][nb];
    }

    // epilogue: out = acc (already modulated), f32 stores
    #pragma unroll
    for (int m = 0; m < 8; m++) {
        size_t rbase = brow + (size_t)(wm * 128 + m * 16 + (H << 2));
        #pragma unroll
        for (int n = 0; n < 4; n++) {
            size_t col = bcol + (size_t)(wn * 64 + n * 16 + L);
            #pragma unroll
            for (int j = 0; j < 4; j++) {
                size_t idx = (rbase + j) * DOUT + col;
                out[idx] = acc[m][n][j];
            }
        }
    }
}

// ---------------------------------------------------------------------------
extern "C" void kernel_launch(void* const* d_in, const int* in_sizes, int n_in,
                              void* d_out, int out_size, void* d_ws, size_t ws_size,
                              hipStream_t stream)
{
    (void)in_sizes; (void)n_in; (void)out_size;
    const float* x  = (const float*)d_in[0];
    const float* cl = (const float*)d_in[1];
    const float* W  = (const float*)d_in[2];
    const float* sL = (const float*)d_in[3];
    const float* sR = (const float*)d_in[4];
    float* out = (float*)d_out;

    // ws: A' (64MiB) | Wt (32MiB) | clb (1MiB) | srt (0.5MiB)
    const size_t AP_BYTES = (size_t)BB * DIN * sizeof(bf16);
    const size_t WT_BYTES = (size_t)DIN * DOUT * sizeof(bf16);
    const size_t CL_BYTES = (size_t)BB * NCL * sizeof(bf16);
    const size_t SR_BYTES = (size_t)DOUT * NCL * sizeof(bf16);
    if (ws_size < AP_BYTES + WT_BYTES + CL_BYTES + SR_BYTES) return;

    char* ws = (char*)d_ws;
    bf16* Ap  = (bf16*)ws;
    bf16* Wt  = (bf16*)(ws + AP_BYTES);
    bf16* clb = (bf16*)(ws + AP_BYTES + WT_BYTES);
    bf16* srt = (bf16*)(ws + AP_BYTES + WT_BYTES + CL_BYTES);

    prologue_kernel<<<dim3(BB / 128, DIN / 128), 256, 0, stream>>>(x, cl, sL, Ap, clb);
    wprep_kernel<<<dim3(2064), 256, 0, stream>>>(W, sR, Wt, srt);
    gemm_kernel<<<dim3((BB / 256) * (DOUT / 256)), 512, 0, stream>>>(Ap, Wt, clb, srt, out);
}

// Round 9
// 300.406 us; speedup vs baseline: 1.2830x; 1.0309x over previous
//
#include <hip/hip_runtime.h>
#include <cstdint>

// Problem constants (from reference): B=8192, DIN=DOUT=4096, NC=64
#define BB   8192
#define DIN  4096
#define DOUT 4096
#define NCL  64

typedef __bf16 bf16;
typedef __attribute__((ext_vector_type(8))) __bf16 bf16x8;
typedef __attribute__((ext_vector_type(4))) float   f32x4;

#define GAS(p) (reinterpret_cast<uint32_t __attribute__((address_space(1)))*>(reinterpret_cast<uintptr_t>(p)))
#define LAS(p) (reinterpret_cast<uint32_t __attribute__((address_space(3)))*>(reinterpret_cast<uintptr_t>(p)))

#define WAITV(n)  asm volatile("s_waitcnt vmcnt(" #n ")" ::: "memory")
#define WAITL()   asm volatile("s_waitcnt lgkmcnt(0)" ::: "memory")
#define BARR()    __builtin_amdgcn_s_barrier()
#define SCHED0()  __builtin_amdgcn_sched_barrier(0)
#define MFMA(a, b, c) __builtin_amdgcn_mfma_f32_16x16x32_bf16((a), (b), (c), 0, 0, 0)

// ---------------------------------------------------------------------------
// Kernel 1: prologue (R7-proven). tmpL = cluster @ style_L (K=64 MFMA);
// A' = bf16(x*tmpL) written via LDS bounce for fully-coalesced x/Ap streams.
// blockIdx.y==0 blocks also dump the cluster tile as bf16 for the GEMM.
// ---------------------------------------------------------------------------
__global__ __launch_bounds__(256) void prologue_kernel(
    const float* __restrict__ x, const float* __restrict__ cl,
    const float* __restrict__ sL, bf16* __restrict__ Ap,
    bf16* __restrict__ clb)
{
    __shared__ char lds[34816]; // 32KB staging, then reused as 128x136 bf16 bounce
    const int t    = threadIdx.x;
    const int lane = t & 63;
    const int w    = t >> 6;
    const int wm   = w >> 1, wn = w & 1;
    const int r0   = blockIdx.x * 128;
    const int c0   = blockIdx.y * 128;

    // stage cluster tile (128x64 f32 -> bf16), swizzled
    #pragma unroll
    for (int i = 0; i < 4; i++) {
        int tk  = t + i * 256;
        int row = tk >> 3, ch = tk & 7;
        const float* src = cl + (size_t)(r0 + row) * NCL + ch * 8;
        float4 v0 = *(const float4*)src;
        float4 v1 = *(const float4*)(src + 4);
        bf16x8 pk;
        pk[0]=(bf16)v0.x; pk[1]=(bf16)v0.y; pk[2]=(bf16)v0.z; pk[3]=(bf16)v0.w;
        pk[4]=(bf16)v1.x; pk[5]=(bf16)v1.y; pk[6]=(bf16)v1.z; pk[7]=(bf16)v1.w;
        *(bf16x8*)(lds + row * 128 + ((ch ^ (row & 7)) << 4)) = pk;
        if (blockIdx.y == 0)
            *(bf16x8*)(clb + (size_t)(r0 + row) * NCL + ch * 8) = pk;
    }
    // stage style_L tile transposed: SL[n][k] = style_L[k][c0+n]
    #pragma unroll
    for (int i = 0; i < 4; i++) {
        int tk = t + i * 256;
        int n  = tk & 127, c = tk >> 7;
        bf16x8 pl;
        #pragma unroll
        for (int j = 0; j < 8; j++)
            pl[j] = (bf16)sL[(size_t)(c * 8 + j) * DIN + c0 + n];
        *(bf16x8*)(lds + 16384 + n * 128 + ((c ^ (n & 7)) << 4)) = pl;
    }
    __syncthreads();

    f32x4 accL[4][4] = {};
    #pragma unroll
    for (int s = 0; s < 2; s++) {
        bf16x8 a[4], bl[4];
        #pragma unroll
        for (int m = 0; m < 4; m++) {
            int row = wm * 64 + m * 16 + (lane & 15);
            int ch  = s * 4 + (lane >> 4);
            a[m] = *(bf16x8*)(lds + row * 128 + ((ch ^ (row & 7)) << 4));
        }
        #pragma unroll
        for (int n = 0; n < 4; n++) {
            int row = wn * 64 + n * 16 + (lane & 15);
            int ch  = s * 4 + (lane >> 4);
            bl[n] = *(bf16x8*)(lds + 16384 + row * 128 + ((ch ^ (row & 7)) << 4));
        }
        #pragma unroll
        for (int m = 0; m < 4; m++)
            #pragma unroll
            for (int n = 0; n < 4; n++)
                accL[m][n] = MFMA(a[m], bl[n], accL[m][n]);
    }
    __syncthreads();   // staging LDS dead; reuse as bounce buffer

    // scatter tmpL (bf16) -> LDS [128 rows][136 cols]
    #pragma unroll
    for (int m = 0; m < 4; m++) {
        int rbase = wm * 64 + m * 16 + ((lane >> 4) << 2);
        #pragma unroll
        for (int n = 0; n < 4; n++) {
            int col = wn * 64 + n * 16 + (lane & 15);
            #pragma unroll
            for (int j = 0; j < 4; j++)
                *(bf16*)(lds + (rbase + j) * 272 + col * 2) = (bf16)accL[m][n][j];
        }
    }
    __syncthreads();

    // coalesced pass: Ap = bf16(x * tmpL); quarter-wave = one row, 512B x-read
    const int L = t & 15, H = (t >> 4) & 3;
    #pragma unroll
    for (int it = 0; it < 8; it++) {
        int row = it * 16 + w * 4 + H;
        bf16x8 tl = *(const bf16x8*)(lds + row * 272 + L * 16);
        const float* xs = x + (size_t)(r0 + row) * DIN + c0 + L * 8;
        float4 x0 = *(const float4*)xs;
        float4 x1 = *(const float4*)(xs + 4);
        bf16x8 o;
        o[0]=(bf16)(x0.x*(float)tl[0]); o[1]=(bf16)(x0.y*(float)tl[1]);
        o[2]=(bf16)(x0.z*(float)tl[2]); o[3]=(bf16)(x0.w*(float)tl[3]);
        o[4]=(bf16)(x1.x*(float)tl[4]); o[5]=(bf16)(x1.y*(float)tl[5]);
        o[6]=(bf16)(x1.z*(float)tl[6]); o[7]=(bf16)(x1.w*(float)tl[7]);
        *(bf16x8*)(Ap + (size_t)(r0 + row) * DIN + c0 + L * 8) = o;
    }
}

// ---------------------------------------------------------------------------
// Kernel 2 (fused streaming prep): block-range dispatch, no LDS, low regs.
//   blocks [0,2048):    W (DIN x DOUT f32) -> Wt (DOUT x DIN bf16)
//   blocks [2048,2064): style_R (64 x DOUT f32) -> sRt (DOUT x 64 bf16)
// ---------------------------------------------------------------------------
__global__ __launch_bounds__(256) void wprep_kernel(
    const float* __restrict__ W, const float* __restrict__ sR,
    bf16* __restrict__ Wt, bf16* __restrict__ srt)
{
    const int bid = blockIdx.x;
    const int t   = threadIdx.x;
    if (bid < 2048) {
        const int n  = (bid & 15) * 256 + t;
        const int k0 = (bid >> 4) * 32;
        bf16x8 v[4];
        #pragma unroll
        for (int q = 0; q < 4; q++)
            #pragma unroll
            for (int j = 0; j < 8; j++)
                v[q][j] = (bf16)W[(size_t)(k0 + q * 8 + j) * DOUT + n];
        bf16* dst = Wt + (size_t)n * DIN + k0;
        #pragma unroll
        for (int q = 0; q < 4; q++)
            *(bf16x8*)(dst + q * 8) = v[q];
    } else {
        const int o = (bid - 2048) * 256 + t;
        bf16x8 v[8];
        #pragma unroll
        for (int q = 0; q < 8; q++)
            #pragma unroll
            for (int j = 0; j < 8; j++)
                v[q][j] = (bf16)sR[(size_t)(q * 8 + j) * DOUT + o];
        bf16* dst = srt + (size_t)o * 64;
        #pragma unroll
        for (int q = 0; q < 8; q++)
            *(bf16x8*)(dst + q * 8) = v[q];
    }
}

// ---------------------------------------------------------------------------
// Kernel 3: 256x256-tile GEMM, 16x16x32 MFMA, 4 barriers/K-tile (was 8).
// Each phase: {ds_reads; stage; [P4: vmcnt(6)]; BAR; lgkm0; MFMA; sched0}.
// The post-MFMA barriers are removed: every stage->slot-death pair is
// protected either by the phase-start barrier + >=600cy MFMA-cluster margin,
// or is the same-phase read||stage overlap already shipping since R7.
// Read balance 12/4/8/0, fused tmpR, XCD 8x8 mapping unchanged.
// ---------------------------------------------------------------------------
template<int CUR>
__device__ __forceinline__ void tile_step(char* lds, int tid,
    const bf16* pA1, const bf16* pA2, const bf16* pA3, const bf16* pA4,
    const bf16* pB1, const bf16* pB2, const bf16* pB3, const bf16* pB4,
    int kA1, int kA2, int aoff0, int aoff1, int boff0, int boff1,
    bf16x8 a[4][2], bf16x8 b[4][2], f32x4 acc[8][4])
{
    constexpr int CB = CUR * 65536;
    constexpr int OB = (CUR ^ 1) * 65536;

    // ---------- P1 ----------
    #pragma unroll
    for (int mq = 0; mq < 4; ++mq) {
        a[mq][0] = *(const bf16x8*)(lds + CB + mq * 2048 + aoff0);
        a[mq][1] = *(const bf16x8*)(lds + CB + mq * 2048 + aoff1);
    }
    #pragma unroll
    for (int nb = 0; nb < 2; ++nb) {
        b[nb][0] = *(const bf16x8*)(lds + CB + nb * 2048 + boff0);
        b[nb][1] = *(const bf16x8*)(lds + CB + nb * 2048 + boff1);
    }
    __builtin_amdgcn_global_load_lds(GAS(pA3 + kA1), LAS(lds + OB + 16384 + tid * 16), 16, 0, 0);
    __builtin_amdgcn_global_load_lds(GAS(pA4 + kA1), LAS(lds + OB + 24576 + tid * 16), 16, 0, 0);
    BARR();
    WAITL(); SCHED0();
    __builtin_amdgcn_s_setprio(1);
    #pragma unroll
    for (int k = 0; k < 2; ++k)
        #pragma unroll
        for (int mq = 0; mq < 4; ++mq)
            #pragma unroll
            for (int nq = 0; nq < 2; ++nq)
                acc[mq][nq] = MFMA(a[mq][k], b[nq][k], acc[mq][nq]);
    __builtin_amdgcn_s_setprio(0);
    SCHED0();

    // ---------- P2 ----------
    #pragma unroll
    for (int nb = 2; nb < 4; ++nb) {
        b[nb][0] = *(const bf16x8*)(lds + CB + nb * 2048 + boff0);
        b[nb][1] = *(const bf16x8*)(lds + CB + nb * 2048 + boff1);
    }
    __builtin_amdgcn_global_load_lds(GAS(pB1 + kA2), LAS(lds + CB + 32768 + tid * 16), 16, 0, 0);
    __builtin_amdgcn_global_load_lds(GAS(pB2 + kA2), LAS(lds + CB + 40960 + tid * 16), 16, 0, 0);
    BARR();
    WAITL(); SCHED0();
    __builtin_amdgcn_s_setprio(1);
    #pragma unroll
    for (int k = 0; k < 2; ++k)
        #pragma unroll
        for (int mq = 0; mq < 4; ++mq)
            #pragma unroll
            for (int nq = 0; nq < 2; ++nq)
                acc[mq][2 + nq] = MFMA(a[mq][k], b[2 + nq][k], acc[mq][2 + nq]);
    __builtin_amdgcn_s_setprio(0);
    SCHED0();

    // ---------- P3 ----------
    #pragma unroll
    for (int mq = 0; mq < 4; ++mq) {
        a[mq][0] = *(const bf16x8*)(lds + CB + 8192 + mq * 2048 + aoff0);
        a[mq][1] = *(const bf16x8*)(lds + CB + 8192 + mq * 2048 + aoff1);
    }
    __builtin_amdgcn_global_load_lds(GAS(pB3 + kA2), LAS(lds + CB + 49152 + tid * 16), 16, 0, 0);
    __builtin_amdgcn_global_load_lds(GAS(pB4 + kA2), LAS(lds + CB + 57344 + tid * 16), 16, 0, 0);
    BARR();
    WAITL(); SCHED0();
    __builtin_amdgcn_s_setprio(1);
    #pragma unroll
    for (int k = 0; k < 2; ++k)
        #pragma unroll
        for (int mq = 0; mq < 4; ++mq)
            #pragma unroll
            for (int nq = 0; nq < 2; ++nq)
                acc[4 + mq][2 + nq] = MFMA(a[mq][k], b[2 + nq][k], acc[4 + mq][2 + nq]);
    __builtin_amdgcn_s_setprio(0);
    SCHED0();

    // ---------- P4 ----------
    __builtin_amdgcn_global_load_lds(GAS(pA1 + kA2), LAS(lds + CB + tid * 16), 16, 0, 0);
    __builtin_amdgcn_global_load_lds(GAS(pA2 + kA2), LAS(lds + CB + 8192 + tid * 16), 16, 0, 0);
    WAITV(6);
    BARR();
    __builtin_amdgcn_s_setprio(1);
    #pragma unroll
    for (int k = 0; k < 2; ++k)
        #pragma unroll
        for (int mq = 0; mq < 4; ++mq)
            #pragma unroll
            for (int nq = 0; nq < 2; ++nq)
                acc[4 + mq][nq] = MFMA(a[mq][k], b[nq][k], acc[4 + mq][nq]);
    __builtin_amdgcn_s_setprio(0);
    SCHED0();
}

__global__ __launch_bounds__(512, 2) void gemm_kernel(
    const bf16* __restrict__ Ap, const bf16* __restrict__ Wt,
    const bf16* __restrict__ clb, const bf16* __restrict__ srt,
    float* __restrict__ out)
{
    __shared__ uint4 smem[8192]; // 128 KiB
    char* lds = (char*)smem;
    const int tid  = threadIdx.x;
    const int lane = tid & 63;
    const int w    = tid >> 6;
    const int wm   = w >> 2;   // 0..1
    const int wn   = w & 3;    // 0..3
    const int L = lane & 15, H = lane >> 4;

    // XCD-bijective swizzle, 8x8 tile block per XCD
    const int bid = blockIdx.x;
    const int xc  = bid & 7, ii = bid >> 3;
    const int mt  = (xc >> 1) * 8 + (ii >> 3);
    const int nt  = (xc & 1) * 8 + (ii & 7);
    const size_t brow = (size_t)mt * 256;
    const size_t bcol = (size_t)nt * 256;

    // staging: dest linear (tid*16), source chunk inverse-swizzled
    const int r1  = tid >> 3;
    const int gch = (tid & 7) ^ (r1 & 7);
    const bf16* pA1 = Ap + (brow + r1) * (size_t)DIN + gch * 8;
    const bf16* pA2 = pA1 + (size_t)64  * DIN;
    const bf16* pA3 = pA1 + (size_t)128 * DIN;
    const bf16* pA4 = pA1 + (size_t)192 * DIN;
    const bf16* pB1 = Wt + (bcol + r1) * (size_t)DIN + gch * 8;
    const bf16* pB2 = pB1 + (size_t)64  * DIN;
    const bf16* pB3 = pB1 + (size_t)128 * DIN;
    const bf16* pB4 = pB1 + (size_t)192 * DIN;

    // fragment ds_read offsets: chunk = kk*4+H, slot = chunk^(L&7)
    const int swz0 = (H ^ (L & 7)) << 4;
    const int swz1 = ((4 + H) ^ (L & 7)) << 4;
    const int aoff0 = wm * 16384 + L * 128 + swz0;
    const int aoff1 = wm * 16384 + L * 128 + swz1;
    const int boff0 = 32768 + (wn >> 1) * 16384 + (wn & 1) * 8192 + L * 128 + swz0;
    const int boff1 = 32768 + (wn >> 1) * 16384 + (wn & 1) * 8192 + L * 128 + swz1;

    bf16x8 a[4][2], b[4][2];
    f32x4 acc[8][4] = {};

    // prologue: tile0 all 4 pieces -> buf0; tile1 {Bh0,Bh1,Ah0} -> buf1
    __builtin_amdgcn_global_load_lds(GAS(pA1), LAS(lds + tid * 16), 16, 0, 0);
    __builtin_amdgcn_global_load_lds(GAS(pA2), LAS(lds + 8192 + tid * 16), 16, 0, 0);
    __builtin_amdgcn_global_load_lds(GAS(pA3), LAS(lds + 16384 + tid * 16), 16, 0, 0);
    __builtin_amdgcn_global_load_lds(GAS(pA4), LAS(lds + 24576 + tid * 16), 16, 0, 0);
    __builtin_amdgcn_global_load_lds(GAS(pB1), LAS(lds + 32768 + tid * 16), 16, 0, 0);
    __builtin_amdgcn_global_load_lds(GAS(pB2), LAS(lds + 40960 + tid * 16), 16, 0, 0);
    __builtin_amdgcn_global_load_lds(GAS(pB3), LAS(lds + 49152 + tid * 16), 16, 0, 0);
    __builtin_amdgcn_global_load_lds(GAS(pB4), LAS(lds + 57344 + tid * 16), 16, 0, 0);
    __builtin_amdgcn_global_load_lds(GAS(pB1 + 64), LAS(lds + 65536 + 32768 + tid * 16), 16, 0, 0);
    __builtin_amdgcn_global_load_lds(GAS(pB2 + 64), LAS(lds + 65536 + 40960 + tid * 16), 16, 0, 0);
    __builtin_amdgcn_global_load_lds(GAS(pB3 + 64), LAS(lds + 65536 + 49152 + tid * 16), 16, 0, 0);
    __builtin_amdgcn_global_load_lds(GAS(pB4 + 64), LAS(lds + 65536 + 57344 + tid * 16), 16, 0, 0);
    __builtin_amdgcn_global_load_lds(GAS(pA1 + 64), LAS(lds + 65536 + tid * 16), 16, 0, 0);
    __builtin_amdgcn_global_load_lds(GAS(pA2 + 64), LAS(lds + 65536 + 8192 + tid * 16), 16, 0, 0);
    WAITV(6);
    BARR();

    #pragma unroll 1
    for (int t = 0; t < 64; t += 2) {
        tile_step<0>(lds, tid, pA1, pA2, pA3, pA4, pB1, pB2, pB3, pB4,
                     ((t + 1) & 63) * 64, ((t + 2) & 63) * 64,
                     aoff0, aoff1, boff0, boff1, a, b, acc);
        tile_step<1>(lds, tid, pA1, pA2, pA3, pA4, pB1, pB2, pB3, pB4,
                     ((t + 2) & 63) * 64, ((t + 3) & 63) * 64,
                     aoff0, aoff1, boff0, boff1, a, b, acc);
    }

    // ---- fused tmpR tile: acc *= (cluster @ style_R) over K=64 ----
    BARR();     // all waves done reading main-loop data before slot reuse
    WAITV(0);   // drain wrap-around junk prefetches BEFORE reusing their LDS slots
    const bf16* pC = clb + (brow + r1) * 64 + gch * 8;
    const bf16* pR = srt + (bcol + r1) * 64 + gch * 8;
    __builtin_amdgcn_global_load_lds(GAS(pC),         LAS(lds + tid * 16), 16, 0, 0);
    __builtin_amdgcn_global_load_lds(GAS(pC + 4096),  LAS(lds + 8192 + tid * 16), 16, 0, 0);
    __builtin_amdgcn_global_load_lds(GAS(pC + 8192),  LAS(lds + 16384 + tid * 16), 16, 0, 0);
    __builtin_amdgcn_global_load_lds(GAS(pC + 12288), LAS(lds + 24576 + tid * 16), 16, 0, 0);
    __builtin_amdgcn_global_load_lds(GAS(pR),         LAS(lds + 32768 + tid * 16), 16, 0, 0);
    __builtin_amdgcn_global_load_lds(GAS(pR + 4096),  LAS(lds + 40960 + tid * 16), 16, 0, 0);
    __builtin_amdgcn_global_load_lds(GAS(pR + 8192),  LAS(lds + 49152 + tid * 16), 16, 0, 0);
    __builtin_amdgcn_global_load_lds(GAS(pR + 12288), LAS(lds + 57344 + tid * 16), 16, 0, 0);
    WAITV(0);
    BARR();

    #pragma unroll
    for (int nb = 0; nb < 4; ++nb) {
        b[nb][0] = *(const bf16x8*)(lds + nb * 2048 + boff0);
        b[nb][1] = *(const bf16x8*)(lds + nb * 2048 + boff1);
    }
    #pragma unroll
    for (int half = 0; half < 2; ++half) {
        #pragma unroll
        for (int mq = 0; mq < 4; ++mq) {
            a[mq][0] = *(const bf16x8*)(lds + half * 8192 + mq * 2048 + aoff0);
            a[mq][1] = *(const bf16x8*)(lds + half * 8192 + mq * 2048 + aoff1);
        }
        WAITL(); SCHED0();
        f32x4 r4[4][4] = {};
        #pragma unroll
        for (int k = 0; k < 2; ++k)
            #pragma unroll
            for (int mq = 0; mq < 4; ++mq)
                #pragma unroll
                for (int nb = 0; nb < 4; ++nb)
                    r4[mq][nb] = MFMA(a[mq][k], b[nb][k], r4[mq][nb]);
        #pragma unroll
        for (int mq = 0; mq < 4; ++mq)
            #pragma unroll
            for (int nb = 0; nb < 4; ++nb)
                acc[half * 4 + mq][nb] *= r4[mq][nb];
    }

    // epilogue: out = acc (already modulated), f32 stores
    #pragma unroll
    for (int m = 0; m < 8; m++) {
        size_t rbase = brow + (size_t)(wm * 128 + m * 16 + (H << 2));
        #pragma unroll
        for (int n = 0; n < 4; n++) {
            size_t col = bcol + (size_t)(wn * 64 + n * 16 + L);
            #pragma unroll
            for (int j = 0; j < 4; j++) {
                size_t idx = (rbase + j) * DOUT + col;
                out[idx] = acc[m][n][j];
            }
        }
    }
}

// ---------------------------------------------------------------------------
extern "C" void kernel_launch(void* const* d_in, const int* in_sizes, int n_in,
                              void* d_out, int out_size, void* d_ws, size_t ws_size,
                              hipStream_t stream)
{
    (void)in_sizes; (void)n_in; (void)out_size;
    const float* x  = (const float*)d_in[0];
    const float* cl = (const float*)d_in[1];
    const float* W  = (const float*)d_in[2];
    const float* sL = (const float*)d_in[3];
    const float* sR = (const float*)d_in[4];
    float* out = (float*)d_out;

    // ws: A' (64MiB) | Wt (32MiB) | clb (1MiB) | srt (0.5MiB)
    const size_t AP_BYTES = (size_t)BB * DIN * sizeof(bf16);
    const size_t WT_BYTES = (size_t)DIN * DOUT * sizeof(bf16);
    const size_t CL_BYTES = (size_t)BB * NCL * sizeof(bf16);
    const size_t SR_BYTES = (size_t)DOUT * NCL * sizeof(bf16);
    if (ws_size < AP_BYTES + WT_BYTES + CL_BYTES + SR_BYTES) return;

    char* ws = (char*)d_ws;
    bf16* Ap  = (bf16*)ws;
    bf16* Wt  = (bf16*)(ws + AP_BYTES);
    bf16* clb = (bf16*)(ws + AP_BYTES + WT_BYTES);
    bf16* srt = (bf16*)(ws + AP_BYTES + WT_BYTES + CL_BYTES);

    prologue_kernel<<<dim3(BB / 128, DIN / 128), 256, 0, stream>>>(x, cl, sL, Ap, clb);
    wprep_kernel<<<dim3(2064), 256, 0, stream>>>(W, sR, Wt, srt);
    gemm_kernel<<<dim3((BB / 256) * (DOUT / 256)), 512, 0, stream>>>(Ap, Wt, clb, srt, out);
}